// Round 10
// baseline (764.277 us; speedup 1.0000x reference)
//
#include <hip/hip_runtime.h>
#include <math.h>

#define N_IN 128

__device__ __forceinline__ float leaky01(float x) { return x >= 0.f ? x : 0.01f * x; }
__device__ __forceinline__ float leaky02(float x) { return x >= 0.f ? x : 0.2f * x; }

// ---------------- CSR build ----------------
__global__ void k_count(const int* __restrict__ edst, int* __restrict__ deg, int E) {
    int e = blockIdx.x * 256 + threadIdx.x;
    if (e < E) atomicAdd(&deg[edst[e]], 1);
}

// hierarchical scan: per-block inclusive scan + block sums
__global__ void k_scan1(const int* __restrict__ deg, int* __restrict__ rowptr,
                        int* __restrict__ bsum, int n) {
    __shared__ int s[256];
    int b = blockIdx.x, t = threadIdx.x;
    int idx = b * 256 + t;
    int v = (idx < n) ? deg[idx] : 0;
    s[t] = v;
    __syncthreads();
    for (int off = 1; off < 256; off <<= 1) {
        int x = (t >= off) ? s[t - off] : 0;
        __syncthreads();
        s[t] += x;
        __syncthreads();
    }
    if (idx < n) rowptr[idx + 1] = s[t];
    if (t == 255) bsum[b] = s[255];
}

__global__ void k_scan2(const int* __restrict__ bsum, int* __restrict__ boff, int nb) {
    __shared__ int s[128];
    int t = threadIdx.x;
    int v = (t < nb) ? bsum[t] : 0;
    s[t] = v;
    __syncthreads();
    for (int off = 1; off < 128; off <<= 1) {
        int x = (t >= off) ? s[t - off] : 0;
        __syncthreads();
        s[t] += x;
        __syncthreads();
    }
    if (t < nb) boff[t] = s[t] - v;   // exclusive
}

__global__ void k_scan3(int* __restrict__ rowptr, const int* __restrict__ boff, int n) {
    int idx = blockIdx.x * 256 + threadIdx.x;
    if (idx < n) rowptr[idx + 1] += boff[idx >> 8];
    if (idx == 0) rowptr[0] = 0;
}

__global__ void k_fill(const int* __restrict__ esrc, const int* __restrict__ edst,
                       const float* __restrict__ ew, const int* __restrict__ rowptr,
                       int* __restrict__ cursor, int* __restrict__ eid,
                       int* __restrict__ csrc, float* __restrict__ clew, int E) {
    int e = blockIdx.x * 256 + threadIdx.x;
    if (e >= E) return;
    int d = edst[e];
    int slot = rowptr[d] + atomicAdd(&cursor[d], 1);
    eid[slot] = e;
    csrc[slot] = esrc[e];
    clew[slot] = log1pf(ew[e]);
}

// deterministic order: insertion-sort each node's segment by edge id
__global__ void k_sortseg(const int* __restrict__ rowptr, int* __restrict__ eid,
                          int* __restrict__ csrc, float* __restrict__ clew, int n) {
    int v = blockIdx.x * 256 + threadIdx.x;
    if (v >= n) return;
    int b = rowptr[v], e = rowptr[v + 1];
    for (int i = b + 1; i < e; i++) {
        int ke = eid[i], ks = csrc[i];
        float kl = clew[i];
        int j = i - 1;
        while (j >= b && eid[j] > ke) {
            eid[j + 1] = eid[j]; csrc[j + 1] = csrc[j]; clew[j + 1] = clew[j];
            j--;
        }
        eid[j + 1] = ke; csrc[j + 1] = ks; clew[j + 1] = kl;
    }
}

// ---------------- pair bucketing (predictor src-gather L2 locality) ----------------
// bucket = src >> 7 (196 buckets). Output per pair is order-independent ->
// nondeterministic perm order still yields deterministic out values.
__global__ void k_bcount(const int* __restrict__ ps, const int* __restrict__ ns,
                         int* __restrict__ bcnt, int npos, int ntot) {
    int p = blockIdx.x * 256 + threadIdx.x;
    if (p >= ntot) return;
    int s = (p < npos) ? ps[p] : ns[p - npos];
    atomicAdd(&bcnt[s >> 7], 1);
}

__global__ void k_bscan(const int* __restrict__ bcnt, int* __restrict__ bbase, int nb) {
    __shared__ int s[256];
    int t = threadIdx.x;
    int v = (t < nb) ? bcnt[t] : 0;
    s[t] = v;
    __syncthreads();
    for (int off = 1; off < 256; off <<= 1) {
        int x = (t >= off) ? s[t - off] : 0;
        __syncthreads();
        s[t] += x;
        __syncthreads();
    }
    if (t < nb) bbase[t] = s[t] - v;   // exclusive
}

__global__ void k_bfill(const int* __restrict__ ps, const int* __restrict__ ns,
                        const int* __restrict__ bbase, int* __restrict__ bcur,
                        int* __restrict__ perm, int npos, int ntot) {
    int p = blockIdx.x * 256 + threadIdx.x;
    if (p >= ntot) return;
    int s = (p < npos) ? ps[p] : ns[p - npos];
    int b = s >> 7;
    int slot = bbase[b] + atomicAdd(&bcur[b], 1);
    perm[slot] = p;
}

// ---------------- fp32 GEMM: C[N,M] = X[N,K] @ W[M,K]^T, fused qa ----------------
__global__ __launch_bounds__(256) void k_gemm(const float* __restrict__ X,
                                              const float* __restrict__ W,
                                              float* __restrict__ C,
                                              int N, int K, int M,
                                              const float* __restrict__ avec,
                                              float* __restrict__ qaOut,
                                              int H, int F) {
    __shared__ float Xs[8][132];
    __shared__ float Ws[8][132];
    __shared__ float qred[128][17];
    int r0 = blockIdx.y * 128;
    int c0 = blockIdx.x * 128;
    int t = threadIdx.x;
    int ty = t >> 4, tx = t & 15;

    float acc[8][8];
#pragma unroll
    for (int i = 0; i < 8; i++)
#pragma unroll
        for (int j = 0; j < 8; j++) acc[i][j] = 0.f;

    int lr = t >> 1;            // 0..127
    int lk = (t & 1) * 4;       // 0 or 4
    bool xok = (r0 + lr) < N;
    const float* Xp = X + (size_t)(r0 + lr) * K + lk;
    const float* Wp = W + (size_t)(c0 + lr) * K + lk;

    for (int k0 = 0; k0 < K; k0 += 8) {
        float4 xv = xok ? *(const float4*)(Xp + k0) : make_float4(0.f, 0.f, 0.f, 0.f);
        float4 wv = *(const float4*)(Wp + k0);
        __syncthreads();
        Xs[lk + 0][lr] = xv.x; Xs[lk + 1][lr] = xv.y; Xs[lk + 2][lr] = xv.z; Xs[lk + 3][lr] = xv.w;
        Ws[lk + 0][lr] = wv.x; Ws[lk + 1][lr] = wv.y; Ws[lk + 2][lr] = wv.z; Ws[lk + 3][lr] = wv.w;
        __syncthreads();
#pragma unroll
        for (int k = 0; k < 8; k++) {
            float4 a0 = *(const float4*)&Xs[k][ty * 8];
            float4 a1 = *(const float4*)&Xs[k][ty * 8 + 4];
            float4 b0 = *(const float4*)&Ws[k][tx * 8];
            float4 b1 = *(const float4*)&Ws[k][tx * 8 + 4];
            float av[8] = {a0.x, a0.y, a0.z, a0.w, a1.x, a1.y, a1.z, a1.w};
            float bv[8] = {b0.x, b0.y, b0.z, b0.w, b1.x, b1.y, b1.z, b1.w};
#pragma unroll
            for (int i = 0; i < 8; i++)
#pragma unroll
                for (int j = 0; j < 8; j++) acc[i][j] += av[i] * bv[j];
        }
    }

#pragma unroll
    for (int i = 0; i < 8; i++) {
        int row = r0 + ty * 8 + i;
        if (row < N) {
            float4 v0 = make_float4(acc[i][0], acc[i][1], acc[i][2], acc[i][3]);
            float4 v1 = make_float4(acc[i][4], acc[i][5], acc[i][6], acc[i][7]);
            *(float4*)&C[(size_t)row * M + c0 + tx * 8] = v0;
            *(float4*)&C[(size_t)row * M + c0 + tx * 8 + 4] = v1;
        }
    }

    if (qaOut) {
        int f0 = (c0 + tx * 8) & (F - 1);
        float4 a0 = *(const float4*)&avec[f0];
        float4 a1 = *(const float4*)&avec[f0 + 4];
#pragma unroll
        for (int i = 0; i < 8; i++) {
            float s = acc[i][0] * a0.x + acc[i][1] * a0.y + acc[i][2] * a0.z + acc[i][3] * a0.w
                    + acc[i][4] * a1.x + acc[i][5] * a1.y + acc[i][6] * a1.z + acc[i][7] * a1.w;
            qred[ty * 8 + i][tx] = s;
        }
        __syncthreads();
        if (t < 128) {
            int R = r0 + t;
            if (R < N) {
                float s0 = 0.f, s1 = 0.f;
#pragma unroll
                for (int x = 0; x < 8; x++) { s0 += qred[t][x]; s1 += qred[t][x + 8]; }
                if (F == 64) {
                    int hb = c0 >> 6;
                    qaOut[(size_t)R * H + hb] = s0;
                    qaOut[(size_t)R * H + hb + 1] = s1;
                } else {
                    qaOut[R] = s0 + s1;
                }
            }
        }
    }
}

// ---------------- per-node softmax stats + alpha: one wave per node ----------------
template <int H>
__global__ __launch_bounds__(256) void k_stats(const float* __restrict__ qa,
                                               const int* __restrict__ rowptr,
                                               const int* __restrict__ csr_src,
                                               const float* __restrict__ csr_lew,
                                               float* __restrict__ alf, int N) {
    int w = threadIdx.x >> 6;
    int l = threadIdx.x & 63;
    int n = blockIdx.x * 4 + w;
    if (n >= N) return;
    int beg = rowptr[n], end = rowptr[n + 1];
    if (beg >= end) return;

    float qd[H];
#pragma unroll
    for (int h = 0; h < H; h++) qd[h] = qa[(size_t)n * H + h];

    float mx[H];
#pragma unroll
    for (int h = 0; h < H; h++) mx[h] = -1e30f;
    for (int i = beg + l; i < end; i += 64) {
        int src = csr_src[i];
        float lw = csr_lew[i];
#pragma unroll
        for (int h = 0; h < H; h++) {
            float sc = leaky01(qa[(size_t)src * H + h] + qd[h] + lw);
            mx[h] = fmaxf(mx[h], sc);
        }
    }
#pragma unroll
    for (int h = 0; h < H; h++) {
        for (int off = 32; off > 0; off >>= 1)
            mx[h] = fmaxf(mx[h], __shfl_xor(mx[h], off, 64));
    }

    float sm[H];
#pragma unroll
    for (int h = 0; h < H; h++) sm[h] = 0.f;
    for (int i = beg + l; i < end; i += 64) {
        int src = csr_src[i];
        float lw = csr_lew[i];
#pragma unroll
        for (int h = 0; h < H; h++) {
            float sc = leaky01(qa[(size_t)src * H + h] + qd[h] + lw);
            sm[h] += __expf(sc - mx[h]);
        }
    }
#pragma unroll
    for (int h = 0; h < H; h++) {
        for (int off = 32; off > 0; off >>= 1)
            sm[h] += __shfl_xor(sm[h], off, 64);
    }
    float inv[H];
#pragma unroll
    for (int h = 0; h < H; h++) inv[h] = 1.f / fmaxf(sm[h], 1e-20f);

    for (int i = beg + l; i < end; i += 64) {
        int src = csr_src[i];
        float lw = csr_lew[i];
        float av[H];
#pragma unroll
        for (int h = 0; h < H; h++) {
            float sc = leaky01(qa[(size_t)src * H + h] + qd[h] + lw);
            av[h] = __expf(sc - mx[h]) * inv[h];
        }
        if (H == 4) {
            *(float4*)&alf[(size_t)i * 4] = make_float4(av[0], av[1], av[2], av[3]);
        } else {
            alf[i] = av[0];
        }
    }
}

// ---------------- weighted aggregation v2: wave per node, vectorized ----------------
template <int H, int F, int VW, bool LOUT>
__global__ __launch_bounds__(256) void k_aggv(const float* __restrict__ feat,
                                              const float* __restrict__ alf,
                                              const float* __restrict__ bias,
                                              const int* __restrict__ rowptr,
                                              const int* __restrict__ csr_src,
                                              float* __restrict__ out, int N) {
    constexpr int M = H * F;
    __shared__ int sh_src[4][64];
    __shared__ float sh_alpha[4][64 * H];
    int w = threadIdx.x >> 6, l = threadIdx.x & 63;
    int n = blockIdx.x * 4 + w;
    if (n >= N) return;
    int beg = rowptr[n];
    int deg = rowptr[n + 1] - beg;
    int c = l * VW;
    const int hh = c / F;

    float acc[VW];
#pragma unroll
    for (int j = 0; j < VW; j++) acc[j] = 0.f;

    for (int c0 = 0; c0 < deg; c0 += 64) {
        int cn = min(64, deg - c0);
        if (l < cn) {
            sh_src[w][l] = csr_src[beg + c0 + l];
            if (H == 4)
                *(float4*)&sh_alpha[w][l * 4] = *(const float4*)&alf[(size_t)(beg + c0 + l) * 4];
            else
                sh_alpha[w][l] = alf[beg + c0 + l];
        }
        int i = 0;
        for (; i + 2 <= cn; i += 2) {
            int s0 = sh_src[w][i], s1 = sh_src[w][i + 1];
            float a0 = sh_alpha[w][i * H + hh], a1 = sh_alpha[w][(i + 1) * H + hh];
            float f0[VW], f1[VW];
            if (VW == 4) {
                float4 v0 = *(const float4*)&feat[(size_t)s0 * M + c];
                float4 v1 = *(const float4*)&feat[(size_t)s1 * M + c];
                f0[0] = v0.x; f0[1] = v0.y; f0[2] = v0.z; f0[3] = v0.w;
                f1[0] = v1.x; f1[1] = v1.y; f1[2] = v1.z; f1[3] = v1.w;
            } else {
                float2 v0 = *(const float2*)&feat[(size_t)s0 * M + c];
                float2 v1 = *(const float2*)&feat[(size_t)s1 * M + c];
                f0[0] = v0.x; f0[1] = v0.y;
                f1[0] = v1.x; f1[1] = v1.y;
            }
#pragma unroll
            for (int j = 0; j < VW; j++) acc[j] += a0 * f0[j] + a1 * f1[j];
        }
        if (i < cn) {
            int s0 = sh_src[w][i];
            float a0 = sh_alpha[w][i * H + hh];
            float f0[VW];
            if (VW == 4) {
                float4 v0 = *(const float4*)&feat[(size_t)s0 * M + c];
                f0[0] = v0.x; f0[1] = v0.y; f0[2] = v0.z; f0[3] = v0.w;
            } else {
                float2 v0 = *(const float2*)&feat[(size_t)s0 * M + c];
                f0[0] = v0.x; f0[1] = v0.y;
            }
#pragma unroll
            for (int j = 0; j < VW; j++) acc[j] += a0 * f0[j];
        }
    }

#pragma unroll
    for (int j = 0; j < VW; j++) {
        float r = acc[j] + bias[c + j];
        if (LOUT) r = leaky01(r);
        out[(size_t)n * M + c + j] = r;
    }
}

// ---------------- fused predictor v9: predf6 + perm + XCD-chunked blocks ----------------
// Identical compute structure to predf6 (72 VGPR proven). Block processes 128
// CONSECUTIVE perm slots; bijective XCD remap makes each XCD's slots contiguous
// -> src-side emb gathers hit that XCD's L2 (bucketed by src>>7).
__global__ __launch_bounds__(256) void k_predf7(const float* __restrict__ h2,
                                                const int* __restrict__ ps, const int* __restrict__ pd,
                                                const int* __restrict__ ns, const int* __restrict__ nd,
                                                const int* __restrict__ perm,
                                                const float* __restrict__ W1, const float* __restrict__ b1,
                                                const float* __restrict__ W2, const float* __restrict__ b2,
                                                const float* __restrict__ W3, const float* __restrict__ b3,
                                                float* __restrict__ out, int npos, int ntot) {
    __shared__ float Zs[128 * 36];   // Z chunk [pair][36]; reused as T1-half [pair][32+pad]
    __shared__ float Wc[32 * 68];    // W1 chunk [k][out]
    __shared__ int sp[128], dp[128], pidx[128];

    int t = threadIdx.x;
    // bijective XCD-chunk remap (m204): blocks on XCD k get consecutive slot chunks
    int G = gridDim.x;
    int b = blockIdx.x;
    int xcd = b & 7;
    int q = G >> 3, r = G & 7;
    int v = (xcd < r ? xcd * (q + 1) : r * (q + 1) + (xcd - r) * q) + (b >> 3);
    int p0 = v * 128;

    int ty2 = t >> 3;       // 0..31 pair groups: pairs ty2 + 32*i, i<4
    int tx2 = t & 7;        // 0..7 out groups: outs tx2*8..+7

    if (t < 128) {
        int pr = p0 + t;
        int s = 0, d = 0, pe = -1;
        if (pr < ntot) {
            pe = perm[pr];
            if (pe < npos) { s = ps[pe]; d = pd[pe]; }
            else           { s = ns[pe - npos]; d = nd[pe - npos]; }
        }
        sp[t] = s; dp[t] = d; pidx[t] = pe;
    }
    __syncthreads();

    float acc[4][8];
#pragma unroll
    for (int i = 0; i < 4; i++)
#pragma unroll
        for (int j = 0; j < 8; j++) acc[i][j] = 0.f;

    int sr = t >> 3;        // staging row within sweep (0..31)
    int sq = t & 7;         // staging quad (0..7)

    for (int kc = 0; kc < 128; kc += 32) {
        // stage Z chunk: 4 sweeps x 32 rows, 8 threads/row (float4 each)
#pragma unroll
        for (int it = 0; it < 4; ++it) {
            int rr = it * 32 + sr;
            int s = sp[rr], d = dp[rr];
            float4 a = *(const float4*)&h2[(size_t)s * 128 + kc + sq * 4];
            float4 bb = *(const float4*)&h2[(size_t)d * 128 + kc + sq * 4];
            *(float4*)&Zs[rr * 36 + sq * 4] =
                make_float4(a.x * bb.x, a.y * bb.y, a.z * bb.z, a.w * bb.w);
        }
        // stage W1 chunk [32 k][64 outs]
        {
            int out_ = t & 63;
            int kh = (t >> 6) * 8;
            const float* wr = W1 + (size_t)out_ * 128 + kc + kh;
#pragma unroll
            for (int c = 0; c < 2; c++) {
                float4 wv = *(const float4*)(wr + c * 4);
                Wc[(kh + c * 4 + 0) * 68 + out_] = wv.x;
                Wc[(kh + c * 4 + 1) * 68 + out_] = wv.y;
                Wc[(kh + c * 4 + 2) * 68 + out_] = wv.z;
                Wc[(kh + c * 4 + 3) * 68 + out_] = wv.w;
            }
        }
        __syncthreads();
#pragma unroll
        for (int k4 = 0; k4 < 8; ++k4) {
            float4 a4[4];
#pragma unroll
            for (int i = 0; i < 4; i++)
                a4[i] = *(const float4*)&Zs[(ty2 + 32 * i) * 36 + k4 * 4];
#pragma unroll
            for (int kk = 0; kk < 4; ++kk) {
                float4 bA = *(const float4*)&Wc[(k4 * 4 + kk) * 68 + tx2 * 8];
                float4 bB = *(const float4*)&Wc[(k4 * 4 + kk) * 68 + tx2 * 8 + 4];
                float bv[8] = {bA.x, bA.y, bA.z, bA.w, bB.x, bB.y, bB.z, bB.w};
#pragma unroll
                for (int i = 0; i < 4; i++) {
                    float a = (kk == 0) ? a4[i].x : (kk == 1) ? a4[i].y : (kk == 2) ? a4[i].z : a4[i].w;
#pragma unroll
                    for (int j = 0; j < 8; j++) acc[i][j] += a * bv[j];
                }
            }
        }
        __syncthreads();
    }

    // bias (pre-activation kept in acc)
    {
        float4 b1a = *(const float4*)&b1[tx2 * 8];
        float4 b1b = *(const float4*)&b1[tx2 * 8 + 4];
        float bb[8] = {b1a.x, b1a.y, b1a.z, b1a.w, b1b.x, b1b.y, b1b.z, b1b.w};
#pragma unroll
        for (int i = 0; i < 4; i++)
#pragma unroll
            for (int j = 0; j < 8; j++) acc[i][j] += bb[j];
    }

    float t2[32];
#pragma unroll
    for (int o = 0; o < 32; o++) t2[o] = b2[o];

    // ---- half A: outs 0..31 (written by tx2 0..3) ----
    if (tx2 < 4) {
#pragma unroll
        for (int i = 0; i < 4; i++) {
            int row = ty2 + 32 * i;
            *(float4*)&Zs[row * 36 + tx2 * 8] =
                make_float4(acc[i][0], acc[i][1], acc[i][2], acc[i][3]);
            *(float4*)&Zs[row * 36 + tx2 * 8 + 4] =
                make_float4(acc[i][4], acc[i][5], acc[i][6], acc[i][7]);
        }
    }
    __syncthreads();
    if (t < 128) {
        for (int j = 0; j < 32; j += 4) {
            float4 v4 = *(const float4*)&Zs[t * 36 + j];
            float v0 = leaky02(v4.x), v1 = leaky02(v4.y), v2 = leaky02(v4.z), v3 = leaky02(v4.w);
#pragma unroll
            for (int o = 0; o < 32; o++) {
                const float* w2 = W2 + (size_t)o * 64 + j;
                t2[o] += v0 * w2[0] + v1 * w2[1] + v2 * w2[2] + v3 * w2[3];
            }
        }
    }
    __syncthreads();
    // ---- half B: outs 32..63 (written by tx2 4..7) ----
    if (tx2 >= 4) {
#pragma unroll
        for (int i = 0; i < 4; i++) {
            int row = ty2 + 32 * i;
            *(float4*)&Zs[row * 36 + (tx2 - 4) * 8] =
                make_float4(acc[i][0], acc[i][1], acc[i][2], acc[i][3]);
            *(float4*)&Zs[row * 36 + (tx2 - 4) * 8 + 4] =
                make_float4(acc[i][4], acc[i][5], acc[i][6], acc[i][7]);
        }
    }
    __syncthreads();
    if (t < 128) {
        for (int j = 0; j < 32; j += 4) {
            float4 v4 = *(const float4*)&Zs[t * 36 + j];
            float v0 = leaky02(v4.x), v1 = leaky02(v4.y), v2 = leaky02(v4.z), v3 = leaky02(v4.w);
#pragma unroll
            for (int o = 0; o < 32; o++) {
                const float* w2 = W2 + (size_t)o * 64 + 32 + j;
                t2[o] += v0 * w2[0] + v1 * w2[1] + v2 * w2[2] + v3 * w2[3];
            }
        }
        float o3 = b3[0];
#pragma unroll
        for (int o = 0; o < 32; o++) o3 += leaky02(t2[o]) * W3[o];
        int pe = pidx[t];
        if (pe >= 0) out[pe] = o3;   // scattered 4B store into 800KB L2-resident buffer
    }
}

extern "C" void kernel_launch(void* const* d_in, const int* in_sizes, int n_in,
                              void* d_out, int out_size, void* d_ws, size_t ws_size,
                              hipStream_t stream) {
    const float* x    = (const float*)d_in[0];
    const float* ew   = (const float*)d_in[1];
    const int* esrc   = (const int*)d_in[2];
    const int* edst   = (const int*)d_in[3];
    const int* pos_s  = (const int*)d_in[4];
    const int* pos_d  = (const int*)d_in[5];
    const int* neg_s  = (const int*)d_in[6];
    const int* neg_d  = (const int*)d_in[7];
    const float* W0 = (const float*)d_in[8];
    const float* a0 = (const float*)d_in[9];
    const float* b0 = (const float*)d_in[10];
    const float* W1 = (const float*)d_in[11];
    const float* a1 = (const float*)d_in[12];
    const float* b1 = (const float*)d_in[13];
    const float* W2 = (const float*)d_in[14];
    const float* a2 = (const float*)d_in[15];
    const float* b2 = (const float*)d_in[16];
    const float* pW1 = (const float*)d_in[17];
    const float* pb1 = (const float*)d_in[18];
    const float* pW2 = (const float*)d_in[19];
    const float* pb2 = (const float*)d_in[20];
    const float* pW3 = (const float*)d_in[21];
    const float* pb3 = (const float*)d_in[22];

    const int N = in_sizes[0] / N_IN;   // 25000
    const int E = in_sizes[1];          // 400000
    const int NP = in_sizes[4];         // 100000

    size_t off = 0;
    auto alloc = [&](size_t bytes) {
        void* p = (char*)d_ws + off;
        off += (bytes + 255) & ~(size_t)255;
        return p;
    };
    int* deg      = (int*)alloc((size_t)N * 4);
    int* cursor   = (int*)alloc((size_t)N * 4);
    int* rowptr   = (int*)alloc((size_t)(N + 1) * 4);
    int* bsum     = (int*)alloc(512);
    int* boff     = (int*)alloc(512);
    int* csr_eid  = (int*)alloc((size_t)E * 4);
    int* csr_src  = (int*)alloc((size_t)E * 4);
    float* csr_lew = (float*)alloc((size_t)E * 4);
    float* qa     = (float*)alloc((size_t)N * 4 * 4);
    float* alf    = (float*)alloc((size_t)E * 4 * 4);
    float* A      = (float*)alloc((size_t)N * 256 * 4);
    float* B      = (float*)alloc((size_t)N * 256 * 4);
    int* bcnt     = (int*)alloc(1024);
    int* bbase    = (int*)alloc(1024);
    int* bcur     = (int*)alloc(1024);
    int* perm     = (int*)alloc((size_t)2 * NP * 4);
    (void)ws_size; (void)n_in; (void)out_size;

    float* out_pred = (float*)d_out;              // [200000]
    float* emb      = (float*)d_out + 2 * NP;     // [25000 x 128]

    hipMemsetAsync(deg, 0, (size_t)N * 4, stream);
    hipMemsetAsync(cursor, 0, (size_t)N * 4, stream);
    hipMemsetAsync(bcnt, 0, 1024, stream);
    hipMemsetAsync(bcur, 0, 1024, stream);

    int eb = (E + 255) / 256;
    int nb = (N + 255) / 256;   // 98
    k_count<<<eb, 256, 0, stream>>>(edst, deg, E);
    k_scan1<<<nb, 256, 0, stream>>>(deg, rowptr, bsum, N);
    k_scan2<<<1, 128, 0, stream>>>(bsum, boff, nb);
    k_scan3<<<nb, 256, 0, stream>>>(rowptr, boff, N);
    k_fill<<<eb, 256, 0, stream>>>(esrc, edst, ew, rowptr, cursor, csr_eid, csr_src, csr_lew, E);
    k_sortseg<<<(N + 255) / 256, 256, 0, stream>>>(rowptr, csr_eid, csr_src, csr_lew, N);

    // pair bucketing for predictor src locality
    int ntot = 2 * NP;
    int pb = (ntot + 255) / 256;
    int NB = (N + 127) / 128;   // 196 buckets
    k_bcount<<<pb, 256, 0, stream>>>(pos_s, neg_s, bcnt, NP, ntot);
    k_bscan<<<1, 256, 0, stream>>>(bcnt, bbase, NB);
    k_bfill<<<pb, 256, 0, stream>>>(pos_s, neg_s, bbase, bcur, perm, NP, ntot);

    int rb = (N + 127) / 128;   // 196
    int sb = (N + 3) / 4;       // wave-per-node blocks

    // layer 0: K=128, M=256
    k_gemm<<<dim3(2, rb), 256, 0, stream>>>(x, W0, A, N, 128, 256, a0, qa, 4, 64);
    k_stats<4><<<sb, 256, 0, stream>>>(qa, rowptr, csr_src, csr_lew, alf, N);
    k_aggv<4, 64, 4, true><<<sb, 256, 0, stream>>>(A, alf, b0, rowptr, csr_src, B, N);

    // layer 1: K=256, M=256
    k_gemm<<<dim3(2, rb), 256, 0, stream>>>(B, W1, A, N, 256, 256, a1, qa, 4, 64);
    k_stats<4><<<sb, 256, 0, stream>>>(qa, rowptr, csr_src, csr_lew, alf, N);
    k_aggv<4, 64, 4, true><<<sb, 256, 0, stream>>>(A, alf, b1, rowptr, csr_src, B, N);

    // layer 2: K=256, M=128
    k_gemm<<<dim3(1, rb), 256, 0, stream>>>(B, W2, A, N, 256, 128, a2, qa, 1, 128);
    k_stats<1><<<sb, 256, 0, stream>>>(qa, rowptr, csr_src, csr_lew, alf, N);
    k_aggv<1, 128, 2, false><<<sb, 256, 0, stream>>>(A, alf, b2, rowptr, csr_src, emb, N);

    // fused predictor on bucketed pairs
    k_predf7<<<(ntot + 127) / 128, 256, 0, stream>>>(emb, pos_s, pos_d, neg_s, neg_d, perm,
                                                     pW1, pb1, pW2, pb2, pW3, pb3,
                                                     out_pred, NP, ntot);
}

// Round 11
// 499.935 us; speedup vs baseline: 1.5288x; 1.5288x over previous
//
#include <hip/hip_runtime.h>
#include <math.h>

#define N_IN 128

__device__ __forceinline__ float leaky01(float x) { return x >= 0.f ? x : 0.01f * x; }
__device__ __forceinline__ float leaky02(float x) { return x >= 0.f ? x : 0.2f * x; }

// ---------------- CSR build ----------------
__global__ void k_count(const int* __restrict__ edst, int* __restrict__ deg, int E) {
    int e = blockIdx.x * 256 + threadIdx.x;
    if (e < E) atomicAdd(&deg[edst[e]], 1);
}

__global__ void k_scan1(const int* __restrict__ deg, int* __restrict__ rowptr,
                        int* __restrict__ bsum, int n) {
    __shared__ int s[256];
    int b = blockIdx.x, t = threadIdx.x;
    int idx = b * 256 + t;
    int v = (idx < n) ? deg[idx] : 0;
    s[t] = v;
    __syncthreads();
    for (int off = 1; off < 256; off <<= 1) {
        int x = (t >= off) ? s[t - off] : 0;
        __syncthreads();
        s[t] += x;
        __syncthreads();
    }
    if (idx < n) rowptr[idx + 1] = s[t];
    if (t == 255) bsum[b] = s[255];
}

__global__ void k_scan2(const int* __restrict__ bsum, int* __restrict__ boff, int nb) {
    __shared__ int s[128];
    int t = threadIdx.x;
    int v = (t < nb) ? bsum[t] : 0;
    s[t] = v;
    __syncthreads();
    for (int off = 1; off < 128; off <<= 1) {
        int x = (t >= off) ? s[t - off] : 0;
        __syncthreads();
        s[t] += x;
        __syncthreads();
    }
    if (t < nb) boff[t] = s[t] - v;   // exclusive
}

__global__ void k_scan3(int* __restrict__ rowptr, const int* __restrict__ boff, int n) {
    int idx = blockIdx.x * 256 + threadIdx.x;
    if (idx < n) rowptr[idx + 1] += boff[idx >> 8];
    if (idx == 0) rowptr[0] = 0;
}

__global__ void k_fill(const int* __restrict__ esrc, const int* __restrict__ edst,
                       const float* __restrict__ ew, const int* __restrict__ rowptr,
                       int* __restrict__ cursor, int* __restrict__ eid,
                       int* __restrict__ csrc, float* __restrict__ clew, int E) {
    int e = blockIdx.x * 256 + threadIdx.x;
    if (e >= E) return;
    int d = edst[e];
    int slot = rowptr[d] + atomicAdd(&cursor[d], 1);
    eid[slot] = e;
    csrc[slot] = esrc[e];
    clew[slot] = log1pf(ew[e]);
}

// deterministic order: insertion-sort each node's segment by edge id
__global__ void k_sortseg(const int* __restrict__ rowptr, int* __restrict__ eid,
                          int* __restrict__ csrc, float* __restrict__ clew, int n) {
    int v = blockIdx.x * 256 + threadIdx.x;
    if (v >= n) return;
    int b = rowptr[v], e = rowptr[v + 1];
    for (int i = b + 1; i < e; i++) {
        int ke = eid[i], ks = csrc[i];
        float kl = clew[i];
        int j = i - 1;
        while (j >= b && eid[j] > ke) {
            eid[j + 1] = eid[j]; csrc[j + 1] = csrc[j]; clew[j + 1] = clew[j];
            j--;
        }
        eid[j + 1] = ke; csrc[j + 1] = ks; clew[j + 1] = kl;
    }
}

// ---------------- fp32 GEMM: C[N,M] = X[N,K] @ W[M,K]^T, fused qa ----------------
__global__ __launch_bounds__(256) void k_gemm(const float* __restrict__ X,
                                              const float* __restrict__ W,
                                              float* __restrict__ C,
                                              int N, int K, int M,
                                              const float* __restrict__ avec,
                                              float* __restrict__ qaOut,
                                              int H, int F) {
    __shared__ float Xs[8][132];
    __shared__ float Ws[8][132];
    __shared__ float qred[128][17];
    int r0 = blockIdx.y * 128;
    int c0 = blockIdx.x * 128;
    int t = threadIdx.x;
    int ty = t >> 4, tx = t & 15;

    float acc[8][8];
#pragma unroll
    for (int i = 0; i < 8; i++)
#pragma unroll
        for (int j = 0; j < 8; j++) acc[i][j] = 0.f;

    int lr = t >> 1;            // 0..127
    int lk = (t & 1) * 4;       // 0 or 4
    bool xok = (r0 + lr) < N;
    const float* Xp = X + (size_t)(r0 + lr) * K + lk;
    const float* Wp = W + (size_t)(c0 + lr) * K + lk;

    for (int k0 = 0; k0 < K; k0 += 8) {
        float4 xv = xok ? *(const float4*)(Xp + k0) : make_float4(0.f, 0.f, 0.f, 0.f);
        float4 wv = *(const float4*)(Wp + k0);
        __syncthreads();
        Xs[lk + 0][lr] = xv.x; Xs[lk + 1][lr] = xv.y; Xs[lk + 2][lr] = xv.z; Xs[lk + 3][lr] = xv.w;
        Ws[lk + 0][lr] = wv.x; Ws[lk + 1][lr] = wv.y; Ws[lk + 2][lr] = wv.z; Ws[lk + 3][lr] = wv.w;
        __syncthreads();
#pragma unroll
        for (int k = 0; k < 8; k++) {
            float4 a0 = *(const float4*)&Xs[k][ty * 8];
            float4 a1 = *(const float4*)&Xs[k][ty * 8 + 4];
            float4 b0 = *(const float4*)&Ws[k][tx * 8];
            float4 b1 = *(const float4*)&Ws[k][tx * 8 + 4];
            float av[8] = {a0.x, a0.y, a0.z, a0.w, a1.x, a1.y, a1.z, a1.w};
            float bv[8] = {b0.x, b0.y, b0.z, b0.w, b1.x, b1.y, b1.z, b1.w};
#pragma unroll
            for (int i = 0; i < 8; i++)
#pragma unroll
                for (int j = 0; j < 8; j++) acc[i][j] += av[i] * bv[j];
        }
    }

#pragma unroll
    for (int i = 0; i < 8; i++) {
        int row = r0 + ty * 8 + i;
        if (row < N) {
            float4 v0 = make_float4(acc[i][0], acc[i][1], acc[i][2], acc[i][3]);
            float4 v1 = make_float4(acc[i][4], acc[i][5], acc[i][6], acc[i][7]);
            *(float4*)&C[(size_t)row * M + c0 + tx * 8] = v0;
            *(float4*)&C[(size_t)row * M + c0 + tx * 8 + 4] = v1;
        }
    }

    if (qaOut) {
        int f0 = (c0 + tx * 8) & (F - 1);
        float4 a0 = *(const float4*)&avec[f0];
        float4 a1 = *(const float4*)&avec[f0 + 4];
#pragma unroll
        for (int i = 0; i < 8; i++) {
            float s = acc[i][0] * a0.x + acc[i][1] * a0.y + acc[i][2] * a0.z + acc[i][3] * a0.w
                    + acc[i][4] * a1.x + acc[i][5] * a1.y + acc[i][6] * a1.z + acc[i][7] * a1.w;
            qred[ty * 8 + i][tx] = s;
        }
        __syncthreads();
        if (t < 128) {
            int R = r0 + t;
            if (R < N) {
                float s0 = 0.f, s1 = 0.f;
#pragma unroll
                for (int x = 0; x < 8; x++) { s0 += qred[t][x]; s1 += qred[t][x + 8]; }
                if (F == 64) {
                    int hb = c0 >> 6;
                    qaOut[(size_t)R * H + hb] = s0;
                    qaOut[(size_t)R * H + hb + 1] = s1;
                } else {
                    qaOut[R] = s0 + s1;
                }
            }
        }
    }
}

// ---------------- fused softmax-stats + aggregation: wave per node ----------------
// Fast path (deg<=128): compute scores ONCE into wave-private LDS, butterfly
// max/sum, scores->alpha in place, then vectorized float4 gather-MAC.
// Slow path (deg>128): gather-recompute (old k_stats logic) + chunked agg.
template <int H, int F, int VW, bool LOUT>
__global__ __launch_bounds__(256) void k_fagg(const float* __restrict__ feat,
                                              const float* __restrict__ qa,
                                              const float* __restrict__ bias,
                                              const int* __restrict__ rowptr,
                                              const int* __restrict__ csr_src,
                                              const float* __restrict__ csr_lew,
                                              float* __restrict__ out, int N) {
    constexpr int M = H * F;
    constexpr int CACHE = 128;
    __shared__ int sh_src[4][CACHE];
    __shared__ float sh_sc[4][CACHE * H];
    int w = threadIdx.x >> 6, l = threadIdx.x & 63;
    int n = blockIdx.x * 4 + w;
    if (n >= N) return;
    int beg = rowptr[n];
    int deg = rowptr[n + 1] - beg;
    int c = l * VW;
    const int hh = c / F;

    float acc[VW];
#pragma unroll
    for (int j = 0; j < VW; j++) acc[j] = 0.f;

    if (deg > 0) {
        float qd[H];
#pragma unroll
        for (int h = 0; h < H; h++) qd[h] = qa[(size_t)n * H + h];

        if (deg <= CACHE) {
            // pass 1: score -> LDS, track max
            float mx[H];
#pragma unroll
            for (int h = 0; h < H; h++) mx[h] = -1e30f;
            for (int i = l; i < deg; i += 64) {
                int src = csr_src[beg + i];
                float lw = csr_lew[beg + i];
                sh_src[w][i] = src;
#pragma unroll
                for (int h = 0; h < H; h++) {
                    float sc = leaky01(qa[(size_t)src * H + h] + qd[h] + lw);
                    sh_sc[w][i * H + h] = sc;
                    mx[h] = fmaxf(mx[h], sc);
                }
            }
#pragma unroll
            for (int h = 0; h < H; h++) {
                for (int off = 32; off > 0; off >>= 1)
                    mx[h] = fmaxf(mx[h], __shfl_xor(mx[h], off, 64));
            }
            // pass 2: sum exp from LDS
            float sm[H];
#pragma unroll
            for (int h = 0; h < H; h++) sm[h] = 0.f;
            for (int i = l; i < deg; i += 64) {
#pragma unroll
                for (int h = 0; h < H; h++) sm[h] += __expf(sh_sc[w][i * H + h] - mx[h]);
            }
#pragma unroll
            for (int h = 0; h < H; h++) {
                for (int off = 32; off > 0; off >>= 1)
                    sm[h] += __shfl_xor(sm[h], off, 64);
            }
            float inv[H];
#pragma unroll
            for (int h = 0; h < H; h++) inv[h] = 1.f / fmaxf(sm[h], 1e-20f);
            // pass 3: scores -> alpha in place
            for (int i = l; i < deg; i += 64) {
#pragma unroll
                for (int h = 0; h < H; h++)
                    sh_sc[w][i * H + h] = __expf(sh_sc[w][i * H + h] - mx[h]) * inv[h];
            }
            // aggregation (wave lockstep; lgkmcnt orders LDS writes before reads)
            int i = 0;
            for (; i + 2 <= deg; i += 2) {
                int s0 = sh_src[w][i], s1 = sh_src[w][i + 1];
                float a0 = sh_sc[w][i * H + hh], a1 = sh_sc[w][(i + 1) * H + hh];
                float f0[VW], f1[VW];
                if (VW == 4) {
                    float4 v0 = *(const float4*)&feat[(size_t)s0 * M + c];
                    float4 v1 = *(const float4*)&feat[(size_t)s1 * M + c];
                    f0[0] = v0.x; f0[1] = v0.y; f0[2] = v0.z; f0[3] = v0.w;
                    f1[0] = v1.x; f1[1] = v1.y; f1[2] = v1.z; f1[3] = v1.w;
                } else {
                    float2 v0 = *(const float2*)&feat[(size_t)s0 * M + c];
                    float2 v1 = *(const float2*)&feat[(size_t)s1 * M + c];
                    f0[0] = v0.x; f0[1] = v0.y;
                    f1[0] = v1.x; f1[1] = v1.y;
                }
#pragma unroll
                for (int j = 0; j < VW; j++) acc[j] += a0 * f0[j] + a1 * f1[j];
            }
            if (i < deg) {
                int s0 = sh_src[w][i];
                float a0 = sh_sc[w][i * H + hh];
                float f0[VW];
                if (VW == 4) {
                    float4 v0 = *(const float4*)&feat[(size_t)s0 * M + c];
                    f0[0] = v0.x; f0[1] = v0.y; f0[2] = v0.z; f0[3] = v0.w;
                } else {
                    float2 v0 = *(const float2*)&feat[(size_t)s0 * M + c];
                    f0[0] = v0.x; f0[1] = v0.y;
                }
#pragma unroll
                for (int j = 0; j < VW; j++) acc[j] += a0 * f0[j];
            }
        } else {
            // slow path: gather-recompute stats, chunked aggregation
            int end = beg + deg;
            float mx[H];
#pragma unroll
            for (int h = 0; h < H; h++) mx[h] = -1e30f;
            for (int i = beg + l; i < end; i += 64) {
                int src = csr_src[i];
                float lw = csr_lew[i];
#pragma unroll
                for (int h = 0; h < H; h++)
                    mx[h] = fmaxf(mx[h], leaky01(qa[(size_t)src * H + h] + qd[h] + lw));
            }
#pragma unroll
            for (int h = 0; h < H; h++) {
                for (int off = 32; off > 0; off >>= 1)
                    mx[h] = fmaxf(mx[h], __shfl_xor(mx[h], off, 64));
            }
            float sm[H];
#pragma unroll
            for (int h = 0; h < H; h++) sm[h] = 0.f;
            for (int i = beg + l; i < end; i += 64) {
                int src = csr_src[i];
                float lw = csr_lew[i];
#pragma unroll
                for (int h = 0; h < H; h++)
                    sm[h] += __expf(leaky01(qa[(size_t)src * H + h] + qd[h] + lw) - mx[h]);
            }
#pragma unroll
            for (int h = 0; h < H; h++) {
                for (int off = 32; off > 0; off >>= 1)
                    sm[h] += __shfl_xor(sm[h], off, 64);
            }
            float inv[H];
#pragma unroll
            for (int h = 0; h < H; h++) inv[h] = 1.f / fmaxf(sm[h], 1e-20f);

            for (int c0 = 0; c0 < deg; c0 += 64) {
                int cn = min(64, deg - c0);
                if (l < cn) {
                    int src = csr_src[beg + c0 + l];
                    float lw = csr_lew[beg + c0 + l];
                    sh_src[w][l] = src;
#pragma unroll
                    for (int h = 0; h < H; h++)
                        sh_sc[w][l * H + h] =
                            __expf(leaky01(qa[(size_t)src * H + h] + qd[h] + lw) - mx[h]) * inv[h];
                }
                for (int i = 0; i < cn; i++) {
                    int s0 = sh_src[w][i];
                    float a0 = sh_sc[w][i * H + hh];
                    if (VW == 4) {
                        float4 v0 = *(const float4*)&feat[(size_t)s0 * M + c];
                        acc[0] += a0 * v0.x; acc[1] += a0 * v0.y;
                        acc[2] += a0 * v0.z; acc[3] += a0 * v0.w;
                    } else {
                        float2 v0 = *(const float2*)&feat[(size_t)s0 * M + c];
                        acc[0] += a0 * v0.x; acc[1] += a0 * v0.y;
                    }
                }
            }
        }
    }

#pragma unroll
    for (int j = 0; j < VW; j++) {
        float r = acc[j] + bias[c + j];
        if (LOUT) r = leaky01(r);
        out[(size_t)n * M + c + j] = r;
    }
}

// ---------------- fused predictor v8 (R8-proven): 256 threads / 128 pairs ----------------
__global__ __launch_bounds__(256) void k_predf6(const float* __restrict__ h2,
                                                const int* __restrict__ ps, const int* __restrict__ pd,
                                                const int* __restrict__ ns, const int* __restrict__ nd,
                                                const float* __restrict__ W1, const float* __restrict__ b1,
                                                const float* __restrict__ W2, const float* __restrict__ b2,
                                                const float* __restrict__ W3, const float* __restrict__ b3,
                                                float* __restrict__ out, int npos, int ntot) {
    __shared__ float Zs[128 * 36];   // Z chunk [pair][36]; reused as T1-half [pair][32+pad]
    __shared__ float Wc[32 * 68];    // W1 chunk [k][out]
    __shared__ int sp[128], dp[128];

    int t = threadIdx.x;
    int p0 = blockIdx.x * 128;
    int ty2 = t >> 3;       // 0..31 pair groups: pairs ty2 + 32*i, i<4
    int tx2 = t & 7;        // 0..7 out groups: outs tx2*8..+7

    if (t < 128) {
        int pr = p0 + t;
        int s = 0, d = 0;
        if (pr < ntot) {
            if (pr < npos) { s = ps[pr]; d = pd[pr]; }
            else           { s = ns[pr - npos]; d = nd[pr - npos]; }
        }
        sp[t] = s; dp[t] = d;
    }
    __syncthreads();

    float acc[4][8];
#pragma unroll
    for (int i = 0; i < 4; i++)
#pragma unroll
        for (int j = 0; j < 8; j++) acc[i][j] = 0.f;

    int sr = t >> 3;        // staging row within sweep (0..31)
    int sq = t & 7;         // staging quad (0..7)

    for (int kc = 0; kc < 128; kc += 32) {
        // stage Z chunk: 4 sweeps x 32 rows, 8 threads/row (float4 each)
#pragma unroll
        for (int it = 0; it < 4; ++it) {
            int r = it * 32 + sr;
            int s = sp[r], d = dp[r];
            float4 a = *(const float4*)&h2[(size_t)s * 128 + kc + sq * 4];
            float4 b = *(const float4*)&h2[(size_t)d * 128 + kc + sq * 4];
            *(float4*)&Zs[r * 36 + sq * 4] =
                make_float4(a.x * b.x, a.y * b.y, a.z * b.z, a.w * b.w);
        }
        // stage W1 chunk [32 k][64 outs]
        {
            int out_ = t & 63;
            int kh = (t >> 6) * 8;
            const float* wr = W1 + (size_t)out_ * 128 + kc + kh;
#pragma unroll
            for (int c = 0; c < 2; c++) {
                float4 wv = *(const float4*)(wr + c * 4);
                Wc[(kh + c * 4 + 0) * 68 + out_] = wv.x;
                Wc[(kh + c * 4 + 1) * 68 + out_] = wv.y;
                Wc[(kh + c * 4 + 2) * 68 + out_] = wv.z;
                Wc[(kh + c * 4 + 3) * 68 + out_] = wv.w;
            }
        }
        __syncthreads();
#pragma unroll
        for (int k4 = 0; k4 < 8; ++k4) {
            float4 a4[4];
#pragma unroll
            for (int i = 0; i < 4; i++)
                a4[i] = *(const float4*)&Zs[(ty2 + 32 * i) * 36 + k4 * 4];
#pragma unroll
            for (int kk = 0; kk < 4; ++kk) {
                float4 bA = *(const float4*)&Wc[(k4 * 4 + kk) * 68 + tx2 * 8];
                float4 bB = *(const float4*)&Wc[(k4 * 4 + kk) * 68 + tx2 * 8 + 4];
                float bv[8] = {bA.x, bA.y, bA.z, bA.w, bB.x, bB.y, bB.z, bB.w};
#pragma unroll
                for (int i = 0; i < 4; i++) {
                    float a = (kk == 0) ? a4[i].x : (kk == 1) ? a4[i].y : (kk == 2) ? a4[i].z : a4[i].w;
#pragma unroll
                    for (int j = 0; j < 8; j++) acc[i][j] += a * bv[j];
                }
            }
        }
        __syncthreads();
    }

    // bias (pre-activation kept in acc)
    {
        float4 b1a = *(const float4*)&b1[tx2 * 8];
        float4 b1b = *(const float4*)&b1[tx2 * 8 + 4];
        float bb[8] = {b1a.x, b1a.y, b1a.z, b1a.w, b1b.x, b1b.y, b1b.z, b1b.w};
#pragma unroll
        for (int i = 0; i < 4; i++)
#pragma unroll
            for (int j = 0; j < 8; j++) acc[i][j] += bb[j];
    }

    float t2[32];
#pragma unroll
    for (int o = 0; o < 32; o++) t2[o] = b2[o];

    // ---- half A: outs 0..31 (written by tx2 0..3) ----
    if (tx2 < 4) {
#pragma unroll
        for (int i = 0; i < 4; i++) {
            int row = ty2 + 32 * i;
            *(float4*)&Zs[row * 36 + tx2 * 8] =
                make_float4(acc[i][0], acc[i][1], acc[i][2], acc[i][3]);
            *(float4*)&Zs[row * 36 + tx2 * 8 + 4] =
                make_float4(acc[i][4], acc[i][5], acc[i][6], acc[i][7]);
        }
    }
    __syncthreads();
    if (t < 128) {
        for (int j = 0; j < 32; j += 4) {
            float4 v4 = *(const float4*)&Zs[t * 36 + j];
            float v0 = leaky02(v4.x), v1 = leaky02(v4.y), v2 = leaky02(v4.z), v3 = leaky02(v4.w);
#pragma unroll
            for (int o = 0; o < 32; o++) {
                const float* w2 = W2 + (size_t)o * 64 + j;
                t2[o] += v0 * w2[0] + v1 * w2[1] + v2 * w2[2] + v3 * w2[3];
            }
        }
    }
    __syncthreads();
    // ---- half B: outs 32..63 (written by tx2 4..7) ----
    if (tx2 >= 4) {
#pragma unroll
        for (int i = 0; i < 4; i++) {
            int row = ty2 + 32 * i;
            *(float4*)&Zs[row * 36 + (tx2 - 4) * 8] =
                make_float4(acc[i][0], acc[i][1], acc[i][2], acc[i][3]);
            *(float4*)&Zs[row * 36 + (tx2 - 4) * 8 + 4] =
                make_float4(acc[i][4], acc[i][5], acc[i][6], acc[i][7]);
        }
    }
    __syncthreads();
    if (t < 128) {
        for (int j = 0; j < 32; j += 4) {
            float4 v4 = *(const float4*)&Zs[t * 36 + j];
            float v0 = leaky02(v4.x), v1 = leaky02(v4.y), v2 = leaky02(v4.z), v3 = leaky02(v4.w);
#pragma unroll
            for (int o = 0; o < 32; o++) {
                const float* w2 = W2 + (size_t)o * 64 + 32 + j;
                t2[o] += v0 * w2[0] + v1 * w2[1] + v2 * w2[2] + v3 * w2[3];
            }
        }
        float o3 = b3[0];
#pragma unroll
        for (int o = 0; o < 32; o++) o3 += leaky02(t2[o]) * W3[o];
        if (p0 + t < ntot) out[p0 + t] = o3;
    }
}

extern "C" void kernel_launch(void* const* d_in, const int* in_sizes, int n_in,
                              void* d_out, int out_size, void* d_ws, size_t ws_size,
                              hipStream_t stream) {
    const float* x    = (const float*)d_in[0];
    const float* ew   = (const float*)d_in[1];
    const int* esrc   = (const int*)d_in[2];
    const int* edst   = (const int*)d_in[3];
    const int* pos_s  = (const int*)d_in[4];
    const int* pos_d  = (const int*)d_in[5];
    const int* neg_s  = (const int*)d_in[6];
    const int* neg_d  = (const int*)d_in[7];
    const float* W0 = (const float*)d_in[8];
    const float* a0 = (const float*)d_in[9];
    const float* b0 = (const float*)d_in[10];
    const float* W1 = (const float*)d_in[11];
    const float* a1 = (const float*)d_in[12];
    const float* b1 = (const float*)d_in[13];
    const float* W2 = (const float*)d_in[14];
    const float* a2 = (const float*)d_in[15];
    const float* b2 = (const float*)d_in[16];
    const float* pW1 = (const float*)d_in[17];
    const float* pb1 = (const float*)d_in[18];
    const float* pW2 = (const float*)d_in[19];
    const float* pb2 = (const float*)d_in[20];
    const float* pW3 = (const float*)d_in[21];
    const float* pb3 = (const float*)d_in[22];

    const int N = in_sizes[0] / N_IN;   // 25000
    const int E = in_sizes[1];          // 400000
    const int NP = in_sizes[4];         // 100000

    size_t off = 0;
    auto alloc = [&](size_t bytes) {
        void* p = (char*)d_ws + off;
        off += (bytes + 255) & ~(size_t)255;
        return p;
    };
    int* deg      = (int*)alloc((size_t)N * 4);
    int* cursor   = (int*)alloc((size_t)N * 4);
    int* rowptr   = (int*)alloc((size_t)(N + 1) * 4);
    int* bsum     = (int*)alloc(512);
    int* boff     = (int*)alloc(512);
    int* csr_eid  = (int*)alloc((size_t)E * 4);
    int* csr_src  = (int*)alloc((size_t)E * 4);
    float* csr_lew = (float*)alloc((size_t)E * 4);
    float* qa     = (float*)alloc((size_t)N * 4 * 4);
    float* A      = (float*)alloc((size_t)N * 256 * 4);
    float* B      = (float*)alloc((size_t)N * 256 * 4);
    (void)ws_size; (void)n_in; (void)out_size;

    float* out_pred = (float*)d_out;              // [200000]
    float* emb      = (float*)d_out + 2 * NP;     // [25000 x 128]

    hipMemsetAsync(deg, 0, (size_t)N * 4, stream);
    hipMemsetAsync(cursor, 0, (size_t)N * 4, stream);

    int eb = (E + 255) / 256;
    int nb = (N + 255) / 256;   // 98
    k_count<<<eb, 256, 0, stream>>>(edst, deg, E);
    k_scan1<<<nb, 256, 0, stream>>>(deg, rowptr, bsum, N);
    k_scan2<<<1, 128, 0, stream>>>(bsum, boff, nb);
    k_scan3<<<nb, 256, 0, stream>>>(rowptr, boff, N);
    k_fill<<<eb, 256, 0, stream>>>(esrc, edst, ew, rowptr, cursor, csr_eid, csr_src, csr_lew, E);
    k_sortseg<<<(N + 255) / 256, 256, 0, stream>>>(rowptr, csr_eid, csr_src, csr_lew, N);

    int rb = (N + 127) / 128;   // 196
    int sb = (N + 3) / 4;       // wave-per-node blocks

    // layer 0: K=128, M=256
    k_gemm<<<dim3(2, rb), 256, 0, stream>>>(x, W0, A, N, 128, 256, a0, qa, 4, 64);
    k_fagg<4, 64, 4, true><<<sb, 256, 0, stream>>>(A, qa, b0, rowptr, csr_src, csr_lew, B, N);

    // layer 1: K=256, M=256
    k_gemm<<<dim3(2, rb), 256, 0, stream>>>(B, W1, A, N, 256, 256, a1, qa, 4, 64);
    k_fagg<4, 64, 4, true><<<sb, 256, 0, stream>>>(A, qa, b1, rowptr, csr_src, csr_lew, B, N);

    // layer 2: K=256, M=128
    k_gemm<<<dim3(1, rb), 256, 0, stream>>>(B, W2, A, N, 256, 128, a2, qa, 1, 128);
    k_fagg<1, 128, 2, false><<<sb, 256, 0, stream>>>(A, qa, b2, rowptr, csr_src, csr_lew, emb, N);

    // fused predictor on 2*NP pairs
    int ntot = 2 * NP;
    k_predf6<<<(ntot + 127) / 128, 256, 0, stream>>>(emb, pos_s, pos_d, neg_s, neg_d,
                                                     pW1, pb1, pW2, pb2, pW3, pb3,
                                                     out_pred, NP, ntot);
}

// Round 12
// 490.442 us; speedup vs baseline: 1.5583x; 1.0194x over previous
//
#include <hip/hip_runtime.h>
#include <math.h>

#define N_IN 128

__device__ __forceinline__ float leaky01(float x) { return x >= 0.f ? x : 0.01f * x; }
__device__ __forceinline__ float leaky02(float x) { return x >= 0.f ? x : 0.2f * x; }

// ---------------- CSR build ----------------
__global__ void k_count(const int* __restrict__ edst, int* __restrict__ deg, int E) {
    int e = blockIdx.x * 256 + threadIdx.x;
    if (e < E) atomicAdd(&deg[edst[e]], 1);
}

__global__ void k_scan1(const int* __restrict__ deg, int* __restrict__ rowptr,
                        int* __restrict__ bsum, int n) {
    __shared__ int s[256];
    int b = blockIdx.x, t = threadIdx.x;
    int idx = b * 256 + t;
    int v = (idx < n) ? deg[idx] : 0;
    s[t] = v;
    __syncthreads();
    for (int off = 1; off < 256; off <<= 1) {
        int x = (t >= off) ? s[t - off] : 0;
        __syncthreads();
        s[t] += x;
        __syncthreads();
    }
    if (idx < n) rowptr[idx + 1] = s[t];
    if (t == 255) bsum[b] = s[255];
}

__global__ void k_scan2(const int* __restrict__ bsum, int* __restrict__ boff, int nb) {
    __shared__ int s[128];
    int t = threadIdx.x;
    int v = (t < nb) ? bsum[t] : 0;
    s[t] = v;
    __syncthreads();
    for (int off = 1; off < 128; off <<= 1) {
        int x = (t >= off) ? s[t - off] : 0;
        __syncthreads();
        s[t] += x;
        __syncthreads();
    }
    if (t < nb) boff[t] = s[t] - v;   // exclusive
}

__global__ void k_scan3(int* __restrict__ rowptr, const int* __restrict__ boff, int n) {
    int idx = blockIdx.x * 256 + threadIdx.x;
    if (idx < n) rowptr[idx + 1] += boff[idx >> 8];
    if (idx == 0) rowptr[0] = 0;
}

__global__ void k_fill(const int* __restrict__ esrc, const int* __restrict__ edst,
                       const float* __restrict__ ew, const int* __restrict__ rowptr,
                       int* __restrict__ cursor, int* __restrict__ eid,
                       int* __restrict__ csrc, float* __restrict__ clew, int E) {
    int e = blockIdx.x * 256 + threadIdx.x;
    if (e >= E) return;
    int d = edst[e];
    int slot = rowptr[d] + atomicAdd(&cursor[d], 1);
    eid[slot] = e;
    csrc[slot] = esrc[e];
    clew[slot] = log1pf(ew[e]);
}

// deterministic order: insertion-sort each node's segment by edge id
__global__ void k_sortseg(const int* __restrict__ rowptr, int* __restrict__ eid,
                          int* __restrict__ csrc, float* __restrict__ clew, int n) {
    int v = blockIdx.x * 256 + threadIdx.x;
    if (v >= n) return;
    int b = rowptr[v], e = rowptr[v + 1];
    for (int i = b + 1; i < e; i++) {
        int ke = eid[i], ks = csrc[i];
        float kl = clew[i];
        int j = i - 1;
        while (j >= b && eid[j] > ke) {
            eid[j + 1] = eid[j]; csrc[j + 1] = csrc[j]; clew[j + 1] = clew[j];
            j--;
        }
        eid[j + 1] = ke; csrc[j + 1] = ks; clew[j + 1] = kl;
    }
}

// ---------------- fp32 GEMM: C[N,M] = X[N,K] @ W[M,K]^T, fused qa ----------------
__global__ __launch_bounds__(256) void k_gemm(const float* __restrict__ X,
                                              const float* __restrict__ W,
                                              float* __restrict__ C,
                                              int N, int K, int M,
                                              const float* __restrict__ avec,
                                              float* __restrict__ qaOut,
                                              int H, int F) {
    __shared__ float Xs[8][132];
    __shared__ float Ws[8][132];
    __shared__ float qred[128][17];
    int r0 = blockIdx.y * 128;
    int c0 = blockIdx.x * 128;
    int t = threadIdx.x;
    int ty = t >> 4, tx = t & 15;

    float acc[8][8];
#pragma unroll
    for (int i = 0; i < 8; i++)
#pragma unroll
        for (int j = 0; j < 8; j++) acc[i][j] = 0.f;

    int lr = t >> 1;            // 0..127
    int lk = (t & 1) * 4;       // 0 or 4
    bool xok = (r0 + lr) < N;
    const float* Xp = X + (size_t)(r0 + lr) * K + lk;
    const float* Wp = W + (size_t)(c0 + lr) * K + lk;

    for (int k0 = 0; k0 < K; k0 += 8) {
        float4 xv = xok ? *(const float4*)(Xp + k0) : make_float4(0.f, 0.f, 0.f, 0.f);
        float4 wv = *(const float4*)(Wp + k0);
        __syncthreads();
        Xs[lk + 0][lr] = xv.x; Xs[lk + 1][lr] = xv.y; Xs[lk + 2][lr] = xv.z; Xs[lk + 3][lr] = xv.w;
        Ws[lk + 0][lr] = wv.x; Ws[lk + 1][lr] = wv.y; Ws[lk + 2][lr] = wv.z; Ws[lk + 3][lr] = wv.w;
        __syncthreads();
#pragma unroll
        for (int k = 0; k < 8; k++) {
            float4 a0 = *(const float4*)&Xs[k][ty * 8];
            float4 a1 = *(const float4*)&Xs[k][ty * 8 + 4];
            float4 b0 = *(const float4*)&Ws[k][tx * 8];
            float4 b1 = *(const float4*)&Ws[k][tx * 8 + 4];
            float av[8] = {a0.x, a0.y, a0.z, a0.w, a1.x, a1.y, a1.z, a1.w};
            float bv[8] = {b0.x, b0.y, b0.z, b0.w, b1.x, b1.y, b1.z, b1.w};
#pragma unroll
            for (int i = 0; i < 8; i++)
#pragma unroll
                for (int j = 0; j < 8; j++) acc[i][j] += av[i] * bv[j];
        }
    }

#pragma unroll
    for (int i = 0; i < 8; i++) {
        int row = r0 + ty * 8 + i;
        if (row < N) {
            float4 v0 = make_float4(acc[i][0], acc[i][1], acc[i][2], acc[i][3]);
            float4 v1 = make_float4(acc[i][4], acc[i][5], acc[i][6], acc[i][7]);
            *(float4*)&C[(size_t)row * M + c0 + tx * 8] = v0;
            *(float4*)&C[(size_t)row * M + c0 + tx * 8 + 4] = v1;
        }
    }

    if (qaOut) {
        int f0 = (c0 + tx * 8) & (F - 1);
        float4 a0 = *(const float4*)&avec[f0];
        float4 a1 = *(const float4*)&avec[f0 + 4];
#pragma unroll
        for (int i = 0; i < 8; i++) {
            float s = acc[i][0] * a0.x + acc[i][1] * a0.y + acc[i][2] * a0.z + acc[i][3] * a0.w
                    + acc[i][4] * a1.x + acc[i][5] * a1.y + acc[i][6] * a1.z + acc[i][7] * a1.w;
            qred[ty * 8 + i][tx] = s;
        }
        __syncthreads();
        if (t < 128) {
            int R = r0 + t;
            if (R < N) {
                float s0 = 0.f, s1 = 0.f;
#pragma unroll
                for (int x = 0; x < 8; x++) { s0 += qred[t][x]; s1 += qred[t][x + 8]; }
                if (F == 64) {
                    int hb = c0 >> 6;
                    qaOut[(size_t)R * H + hb] = s0;
                    qaOut[(size_t)R * H + hb + 1] = s1;
                } else {
                    qaOut[R] = s0 + s1;
                }
            }
        }
    }
}

// ---------------- fused softmax-stats + aggregation v2: wave per node ----------------
// Score phase: lane l -> (edge l/H, head l%H): all 64 lanes active (vs deg of 64).
// Butterfly reduce with xor {32..H} stays within head groups. Agg loop: ILP4.
template <int H, int F, int VW, bool LOUT>
__global__ __launch_bounds__(256) void k_fagg(const float* __restrict__ feat,
                                              const float* __restrict__ qa,
                                              const float* __restrict__ bias,
                                              const int* __restrict__ rowptr,
                                              const int* __restrict__ csr_src,
                                              const float* __restrict__ csr_lew,
                                              float* __restrict__ out, int N) {
    constexpr int M = H * F;
    constexpr int CACHE = 128;
    constexpr int EPP = 64 / H;   // edges per score pass
    __shared__ int sh_src[4][CACHE];
    __shared__ float sh_sc[4][CACHE * H];
    int w = threadIdx.x >> 6, l = threadIdx.x & 63;
    int n = blockIdx.x * 4 + w;
    if (n >= N) return;
    int beg = rowptr[n];
    int deg = rowptr[n + 1] - beg;
    int c = l * VW;
    const int hh = c / F;

    float acc0[VW], acc1[VW];
#pragma unroll
    for (int j = 0; j < VW; j++) { acc0[j] = 0.f; acc1[j] = 0.f; }

    if (deg > 0) {
        if (deg <= CACHE) {
            // lane -> (edge, head)
            const int e0 = l / H;
            const int h = l & (H - 1);
            float qd = qa[(size_t)n * H + h];
            // pass 1: scores -> LDS, per-lane max
            float mx = -1e30f;
            for (int i0 = 0; i0 < deg; i0 += EPP) {
                int e = i0 + e0;
                if (e < deg) {
                    int src = csr_src[beg + e];
                    float lw = csr_lew[beg + e];
                    if (h == 0) sh_src[w][e] = src;
                    float sc = leaky01(qa[(size_t)src * H + h] + qd + lw);
                    sh_sc[w][e * H + h] = sc;
                    mx = fmaxf(mx, sc);
                }
            }
            for (int off = 32; off >= H; off >>= 1)
                mx = fmaxf(mx, __shfl_xor(mx, off, 64));
            // pass 2: sum of exp (fixed-order butterfly)
            float sm = 0.f;
            for (int i0 = 0; i0 < deg; i0 += EPP) {
                int e = i0 + e0;
                if (e < deg) sm += __expf(sh_sc[w][e * H + h] - mx);
            }
            for (int off = 32; off >= H; off >>= 1)
                sm += __shfl_xor(sm, off, 64);
            float inv = 1.f / fmaxf(sm, 1e-20f);
            // pass 3: scores -> alpha in place
            for (int i0 = 0; i0 < deg; i0 += EPP) {
                int e = i0 + e0;
                if (e < deg)
                    sh_sc[w][e * H + h] = __expf(sh_sc[w][e * H + h] - mx) * inv;
            }
            // aggregation: ILP4 (4 gathers in flight), wave-lockstep LDS
            int i = 0;
            for (; i + 4 <= deg; i += 4) {
                int s0 = sh_src[w][i], s1 = sh_src[w][i + 1];
                int s2 = sh_src[w][i + 2], s3 = sh_src[w][i + 3];
                float a0 = sh_sc[w][i * H + hh], a1 = sh_sc[w][(i + 1) * H + hh];
                float a2 = sh_sc[w][(i + 2) * H + hh], a3 = sh_sc[w][(i + 3) * H + hh];
                float f0[VW], f1[VW], f2[VW], f3[VW];
                if (VW == 4) {
                    float4 v0 = *(const float4*)&feat[(size_t)s0 * M + c];
                    float4 v1 = *(const float4*)&feat[(size_t)s1 * M + c];
                    float4 v2 = *(const float4*)&feat[(size_t)s2 * M + c];
                    float4 v3 = *(const float4*)&feat[(size_t)s3 * M + c];
                    f0[0] = v0.x; f0[1] = v0.y; f0[2] = v0.z; f0[3] = v0.w;
                    f1[0] = v1.x; f1[1] = v1.y; f1[2] = v1.z; f1[3] = v1.w;
                    f2[0] = v2.x; f2[1] = v2.y; f2[2] = v2.z; f2[3] = v2.w;
                    f3[0] = v3.x; f3[1] = v3.y; f3[2] = v3.z; f3[3] = v3.w;
                } else {
                    float2 v0 = *(const float2*)&feat[(size_t)s0 * M + c];
                    float2 v1 = *(const float2*)&feat[(size_t)s1 * M + c];
                    float2 v2 = *(const float2*)&feat[(size_t)s2 * M + c];
                    float2 v3 = *(const float2*)&feat[(size_t)s3 * M + c];
                    f0[0] = v0.x; f0[1] = v0.y;
                    f1[0] = v1.x; f1[1] = v1.y;
                    f2[0] = v2.x; f2[1] = v2.y;
                    f3[0] = v3.x; f3[1] = v3.y;
                }
#pragma unroll
                for (int j = 0; j < VW; j++) {
                    acc0[j] += a0 * f0[j] + a1 * f1[j];
                    acc1[j] += a2 * f2[j] + a3 * f3[j];
                }
            }
            for (; i < deg; ++i) {
                int s0 = sh_src[w][i];
                float a0 = sh_sc[w][i * H + hh];
                if (VW == 4) {
                    float4 v0 = *(const float4*)&feat[(size_t)s0 * M + c];
                    acc0[0] += a0 * v0.x; acc0[1] += a0 * v0.y;
                    acc0[2] += a0 * v0.z; acc0[3] += a0 * v0.w;
                } else {
                    float2 v0 = *(const float2*)&feat[(size_t)s0 * M + c];
                    acc0[0] += a0 * v0.x; acc0[1] += a0 * v0.y;
                }
            }
        } else {
            // slow path (deg > CACHE): gather-recompute stats, chunked agg
            float qd[H];
#pragma unroll
            for (int h = 0; h < H; h++) qd[h] = qa[(size_t)n * H + h];
            int end = beg + deg;
            float mx[H];
#pragma unroll
            for (int h = 0; h < H; h++) mx[h] = -1e30f;
            for (int i = beg + l; i < end; i += 64) {
                int src = csr_src[i];
                float lw = csr_lew[i];
#pragma unroll
                for (int h = 0; h < H; h++)
                    mx[h] = fmaxf(mx[h], leaky01(qa[(size_t)src * H + h] + qd[h] + lw));
            }
#pragma unroll
            for (int h = 0; h < H; h++) {
                for (int off = 32; off > 0; off >>= 1)
                    mx[h] = fmaxf(mx[h], __shfl_xor(mx[h], off, 64));
            }
            float sm[H];
#pragma unroll
            for (int h = 0; h < H; h++) sm[h] = 0.f;
            for (int i = beg + l; i < end; i += 64) {
                int src = csr_src[i];
                float lw = csr_lew[i];
#pragma unroll
                for (int h = 0; h < H; h++)
                    sm[h] += __expf(leaky01(qa[(size_t)src * H + h] + qd[h] + lw) - mx[h]);
            }
#pragma unroll
            for (int h = 0; h < H; h++) {
                for (int off = 32; off > 0; off >>= 1)
                    sm[h] += __shfl_xor(sm[h], off, 64);
            }
            float inv[H];
#pragma unroll
            for (int h = 0; h < H; h++) inv[h] = 1.f / fmaxf(sm[h], 1e-20f);

            for (int c0 = 0; c0 < deg; c0 += 64) {
                int cn = min(64, deg - c0);
                if (l < cn) {
                    int src = csr_src[beg + c0 + l];
                    float lw = csr_lew[beg + c0 + l];
                    sh_src[w][l] = src;
#pragma unroll
                    for (int h = 0; h < H; h++)
                        sh_sc[w][l * H + h] =
                            __expf(leaky01(qa[(size_t)src * H + h] + qd[h] + lw) - mx[h]) * inv[h];
                }
                for (int i = 0; i < cn; i++) {
                    int s0 = sh_src[w][i];
                    float a0 = sh_sc[w][i * H + hh];
                    if (VW == 4) {
                        float4 v0 = *(const float4*)&feat[(size_t)s0 * M + c];
                        acc0[0] += a0 * v0.x; acc0[1] += a0 * v0.y;
                        acc0[2] += a0 * v0.z; acc0[3] += a0 * v0.w;
                    } else {
                        float2 v0 = *(const float2*)&feat[(size_t)s0 * M + c];
                        acc0[0] += a0 * v0.x; acc0[1] += a0 * v0.y;
                    }
                }
            }
        }
    }

#pragma unroll
    for (int j = 0; j < VW; j++) {
        float r = acc0[j] + acc1[j] + bias[c + j];
        if (LOUT) r = leaky01(r);
        out[(size_t)n * M + c + j] = r;
    }
}

// ---------------- fused predictor v8 (R8-proven): 256 threads / 128 pairs ----------------
__global__ __launch_bounds__(256) void k_predf6(const float* __restrict__ h2,
                                                const int* __restrict__ ps, const int* __restrict__ pd,
                                                const int* __restrict__ ns, const int* __restrict__ nd,
                                                const float* __restrict__ W1, const float* __restrict__ b1,
                                                const float* __restrict__ W2, const float* __restrict__ b2,
                                                const float* __restrict__ W3, const float* __restrict__ b3,
                                                float* __restrict__ out, int npos, int ntot) {
    __shared__ float Zs[128 * 36];   // Z chunk [pair][36]; reused as T1-half [pair][32+pad]
    __shared__ float Wc[32 * 68];    // W1 chunk [k][out]
    __shared__ int sp[128], dp[128];

    int t = threadIdx.x;
    int p0 = blockIdx.x * 128;
    int ty2 = t >> 3;       // 0..31 pair groups: pairs ty2 + 32*i, i<4
    int tx2 = t & 7;        // 0..7 out groups: outs tx2*8..+7

    if (t < 128) {
        int pr = p0 + t;
        int s = 0, d = 0;
        if (pr < ntot) {
            if (pr < npos) { s = ps[pr]; d = pd[pr]; }
            else           { s = ns[pr - npos]; d = nd[pr - npos]; }
        }
        sp[t] = s; dp[t] = d;
    }
    __syncthreads();

    float acc[4][8];
#pragma unroll
    for (int i = 0; i < 4; i++)
#pragma unroll
        for (int j = 0; j < 8; j++) acc[i][j] = 0.f;

    int sr = t >> 3;        // staging row within sweep (0..31)
    int sq = t & 7;         // staging quad (0..7)

    for (int kc = 0; kc < 128; kc += 32) {
        // stage Z chunk: 4 sweeps x 32 rows, 8 threads/row (float4 each)
#pragma unroll
        for (int it = 0; it < 4; ++it) {
            int r = it * 32 + sr;
            int s = sp[r], d = dp[r];
            float4 a = *(const float4*)&h2[(size_t)s * 128 + kc + sq * 4];
            float4 b = *(const float4*)&h2[(size_t)d * 128 + kc + sq * 4];
            *(float4*)&Zs[r * 36 + sq * 4] =
                make_float4(a.x * b.x, a.y * b.y, a.z * b.z, a.w * b.w);
        }
        // stage W1 chunk [32 k][64 outs]
        {
            int out_ = t & 63;
            int kh = (t >> 6) * 8;
            const float* wr = W1 + (size_t)out_ * 128 + kc + kh;
#pragma unroll
            for (int c = 0; c < 2; c++) {
                float4 wv = *(const float4*)(wr + c * 4);
                Wc[(kh + c * 4 + 0) * 68 + out_] = wv.x;
                Wc[(kh + c * 4 + 1) * 68 + out_] = wv.y;
                Wc[(kh + c * 4 + 2) * 68 + out_] = wv.z;
                Wc[(kh + c * 4 + 3) * 68 + out_] = wv.w;
            }
        }
        __syncthreads();
#pragma unroll
        for (int k4 = 0; k4 < 8; ++k4) {
            float4 a4[4];
#pragma unroll
            for (int i = 0; i < 4; i++)
                a4[i] = *(const float4*)&Zs[(ty2 + 32 * i) * 36 + k4 * 4];
#pragma unroll
            for (int kk = 0; kk < 4; ++kk) {
                float4 bA = *(const float4*)&Wc[(k4 * 4 + kk) * 68 + tx2 * 8];
                float4 bB = *(const float4*)&Wc[(k4 * 4 + kk) * 68 + tx2 * 8 + 4];
                float bv[8] = {bA.x, bA.y, bA.z, bA.w, bB.x, bB.y, bB.z, bB.w};
#pragma unroll
                for (int i = 0; i < 4; i++) {
                    float a = (kk == 0) ? a4[i].x : (kk == 1) ? a4[i].y : (kk == 2) ? a4[i].z : a4[i].w;
#pragma unroll
                    for (int j = 0; j < 8; j++) acc[i][j] += a * bv[j];
                }
            }
        }
        __syncthreads();
    }

    // bias (pre-activation kept in acc)
    {
        float4 b1a = *(const float4*)&b1[tx2 * 8];
        float4 b1b = *(const float4*)&b1[tx2 * 8 + 4];
        float bb[8] = {b1a.x, b1a.y, b1a.z, b1a.w, b1b.x, b1b.y, b1b.z, b1b.w};
#pragma unroll
        for (int i = 0; i < 4; i++)
#pragma unroll
            for (int j = 0; j < 8; j++) acc[i][j] += bb[j];
    }

    float t2[32];
#pragma unroll
    for (int o = 0; o < 32; o++) t2[o] = b2[o];

    // ---- half A: outs 0..31 (written by tx2 0..3) ----
    if (tx2 < 4) {
#pragma unroll
        for (int i = 0; i < 4; i++) {
            int row = ty2 + 32 * i;
            *(float4*)&Zs[row * 36 + tx2 * 8] =
                make_float4(acc[i][0], acc[i][1], acc[i][2], acc[i][3]);
            *(float4*)&Zs[row * 36 + tx2 * 8 + 4] =
                make_float4(acc[i][4], acc[i][5], acc[i][6], acc[i][7]);
        }
    }
    __syncthreads();
    if (t < 128) {
        for (int j = 0; j < 32; j += 4) {
            float4 v4 = *(const float4*)&Zs[t * 36 + j];
            float v0 = leaky02(v4.x), v1 = leaky02(v4.y), v2 = leaky02(v4.z), v3 = leaky02(v4.w);
#pragma unroll
            for (int o = 0; o < 32; o++) {
                const float* w2 = W2 + (size_t)o * 64 + j;
                t2[o] += v0 * w2[0] + v1 * w2[1] + v2 * w2[2] + v3 * w2[3];
            }
        }
    }
    __syncthreads();
    // ---- half B: outs 32..63 (written by tx2 4..7) ----
    if (tx2 >= 4) {
#pragma unroll
        for (int i = 0; i < 4; i++) {
            int row = ty2 + 32 * i;
            *(float4*)&Zs[row * 36 + (tx2 - 4) * 8] =
                make_float4(acc[i][0], acc[i][1], acc[i][2], acc[i][3]);
            *(float4*)&Zs[row * 36 + (tx2 - 4) * 8 + 4] =
                make_float4(acc[i][4], acc[i][5], acc[i][6], acc[i][7]);
        }
    }
    __syncthreads();
    if (t < 128) {
        for (int j = 0; j < 32; j += 4) {
            float4 v4 = *(const float4*)&Zs[t * 36 + j];
            float v0 = leaky02(v4.x), v1 = leaky02(v4.y), v2 = leaky02(v4.z), v3 = leaky02(v4.w);
#pragma unroll
            for (int o = 0; o < 32; o++) {
                const float* w2 = W2 + (size_t)o * 64 + 32 + j;
                t2[o] += v0 * w2[0] + v1 * w2[1] + v2 * w2[2] + v3 * w2[3];
            }
        }
        float o3 = b3[0];
#pragma unroll
        for (int o = 0; o < 32; o++) o3 += leaky02(t2[o]) * W3[o];
        if (p0 + t < ntot) out[p0 + t] = o3;
    }
}

extern "C" void kernel_launch(void* const* d_in, const int* in_sizes, int n_in,
                              void* d_out, int out_size, void* d_ws, size_t ws_size,
                              hipStream_t stream) {
    const float* x    = (const float*)d_in[0];
    const float* ew   = (const float*)d_in[1];
    const int* esrc   = (const int*)d_in[2];
    const int* edst   = (const int*)d_in[3];
    const int* pos_s  = (const int*)d_in[4];
    const int* pos_d  = (const int*)d_in[5];
    const int* neg_s  = (const int*)d_in[6];
    const int* neg_d  = (const int*)d_in[7];
    const float* W0 = (const float*)d_in[8];
    const float* a0 = (const float*)d_in[9];
    const float* b0 = (const float*)d_in[10];
    const float* W1 = (const float*)d_in[11];
    const float* a1 = (const float*)d_in[12];
    const float* b1 = (const float*)d_in[13];
    const float* W2 = (const float*)d_in[14];
    const float* a2 = (const float*)d_in[15];
    const float* b2 = (const float*)d_in[16];
    const float* pW1 = (const float*)d_in[17];
    const float* pb1 = (const float*)d_in[18];
    const float* pW2 = (const float*)d_in[19];
    const float* pb2 = (const float*)d_in[20];
    const float* pW3 = (const float*)d_in[21];
    const float* pb3 = (const float*)d_in[22];

    const int N = in_sizes[0] / N_IN;   // 25000
    const int E = in_sizes[1];          // 400000
    const int NP = in_sizes[4];         // 100000

    size_t off = 0;
    auto alloc = [&](size_t bytes) {
        void* p = (char*)d_ws + off;
        off += (bytes + 255) & ~(size_t)255;
        return p;
    };
    int* deg      = (int*)alloc((size_t)N * 4);
    int* cursor   = (int*)alloc((size_t)N * 4);
    int* rowptr   = (int*)alloc((size_t)(N + 1) * 4);
    int* bsum     = (int*)alloc(512);
    int* boff     = (int*)alloc(512);
    int* csr_eid  = (int*)alloc((size_t)E * 4);
    int* csr_src  = (int*)alloc((size_t)E * 4);
    float* csr_lew = (float*)alloc((size_t)E * 4);
    float* qa     = (float*)alloc((size_t)N * 4 * 4);
    float* A      = (float*)alloc((size_t)N * 256 * 4);
    float* B      = (float*)alloc((size_t)N * 256 * 4);
    (void)ws_size; (void)n_in; (void)out_size;

    float* out_pred = (float*)d_out;              // [200000]
    float* emb      = (float*)d_out + 2 * NP;     // [25000 x 128]

    hipMemsetAsync(deg, 0, (size_t)N * 4, stream);
    hipMemsetAsync(cursor, 0, (size_t)N * 4, stream);

    int eb = (E + 255) / 256;
    int nb = (N + 255) / 256;   // 98
    k_count<<<eb, 256, 0, stream>>>(edst, deg, E);
    k_scan1<<<nb, 256, 0, stream>>>(deg, rowptr, bsum, N);
    k_scan2<<<1, 128, 0, stream>>>(bsum, boff, nb);
    k_scan3<<<nb, 256, 0, stream>>>(rowptr, boff, N);
    k_fill<<<eb, 256, 0, stream>>>(esrc, edst, ew, rowptr, cursor, csr_eid, csr_src, csr_lew, E);
    k_sortseg<<<(N + 255) / 256, 256, 0, stream>>>(rowptr, csr_eid, csr_src, csr_lew, N);

    int rb = (N + 127) / 128;   // 196
    int sb = (N + 3) / 4;       // wave-per-node blocks

    // layer 0: K=128, M=256
    k_gemm<<<dim3(2, rb), 256, 0, stream>>>(x, W0, A, N, 128, 256, a0, qa, 4, 64);
    k_fagg<4, 64, 4, true><<<sb, 256, 0, stream>>>(A, qa, b0, rowptr, csr_src, csr_lew, B, N);

    // layer 1: K=256, M=256
    k_gemm<<<dim3(2, rb), 256, 0, stream>>>(B, W1, A, N, 256, 256, a1, qa, 4, 64);
    k_fagg<4, 64, 4, true><<<sb, 256, 0, stream>>>(A, qa, b1, rowptr, csr_src, csr_lew, B, N);

    // layer 2: K=256, M=128
    k_gemm<<<dim3(1, rb), 256, 0, stream>>>(B, W2, A, N, 256, 128, a2, qa, 1, 128);
    k_fagg<1, 128, 2, false><<<sb, 256, 0, stream>>>(A, qa, b2, rowptr, csr_src, csr_lew, emb, N);

    // fused predictor on 2*NP pairs
    int ntot = 2 * NP;
    k_predf6<<<(ntot + 127) / 128, 256, 0, stream>>>(emb, pos_s, pos_d, neg_s, neg_d,
                                                     pW1, pb1, pW2, pb2, pW3, pb3,
                                                     out_pred, NP, ntot);
}

// Round 13
// 487.776 us; speedup vs baseline: 1.5669x; 1.0055x over previous
//
#include <hip/hip_runtime.h>
#include <math.h>

#define N_IN 128

__device__ __forceinline__ float leaky01(float x) { return x >= 0.f ? x : 0.01f * x; }
__device__ __forceinline__ float leaky02(float x) { return x >= 0.f ? x : 0.2f * x; }

// ---------------- CSR build ----------------
__global__ void k_count(const int* __restrict__ edst, int* __restrict__ deg, int E) {
    int e = blockIdx.x * 256 + threadIdx.x;
    if (e < E) atomicAdd(&deg[edst[e]], 1);
}

__global__ void k_scan1(const int* __restrict__ deg, int* __restrict__ rowptr,
                        int* __restrict__ bsum, int n) {
    __shared__ int s[256];
    int b = blockIdx.x, t = threadIdx.x;
    int idx = b * 256 + t;
    int v = (idx < n) ? deg[idx] : 0;
    s[t] = v;
    __syncthreads();
    for (int off = 1; off < 256; off <<= 1) {
        int x = (t >= off) ? s[t - off] : 0;
        __syncthreads();
        s[t] += x;
        __syncthreads();
    }
    if (idx < n) rowptr[idx + 1] = s[t];
    if (t == 255) bsum[b] = s[255];
}

__global__ void k_scan2(const int* __restrict__ bsum, int* __restrict__ boff, int nb) {
    __shared__ int s[128];
    int t = threadIdx.x;
    int v = (t < nb) ? bsum[t] : 0;
    s[t] = v;
    __syncthreads();
    for (int off = 1; off < 128; off <<= 1) {
        int x = (t >= off) ? s[t - off] : 0;
        __syncthreads();
        s[t] += x;
        __syncthreads();
    }
    if (t < nb) boff[t] = s[t] - v;   // exclusive
}

__global__ void k_scan3(int* __restrict__ rowptr, const int* __restrict__ boff, int n) {
    int idx = blockIdx.x * 256 + threadIdx.x;
    if (idx < n) rowptr[idx + 1] += boff[idx >> 8];
    if (idx == 0) rowptr[0] = 0;
}

__global__ void k_fill(const int* __restrict__ esrc, const int* __restrict__ edst,
                       const float* __restrict__ ew, const int* __restrict__ rowptr,
                       int* __restrict__ cursor, int* __restrict__ eid,
                       int* __restrict__ csrc, float* __restrict__ clew, int E) {
    int e = blockIdx.x * 256 + threadIdx.x;
    if (e >= E) return;
    int d = edst[e];
    int slot = rowptr[d] + atomicAdd(&cursor[d], 1);
    eid[slot] = e;
    csrc[slot] = esrc[e];
    clew[slot] = log1pf(ew[e]);
}

// deterministic order: insertion-sort each node's segment by edge id
__global__ void k_sortseg(const int* __restrict__ rowptr, int* __restrict__ eid,
                          int* __restrict__ csrc, float* __restrict__ clew, int n) {
    int v = blockIdx.x * 256 + threadIdx.x;
    if (v >= n) return;
    int b = rowptr[v], e = rowptr[v + 1];
    for (int i = b + 1; i < e; i++) {
        int ke = eid[i], ks = csrc[i];
        float kl = clew[i];
        int j = i - 1;
        while (j >= b && eid[j] > ke) {
            eid[j + 1] = eid[j]; csrc[j + 1] = csrc[j]; clew[j + 1] = clew[j];
            j--;
        }
        eid[j + 1] = ke; csrc[j + 1] = ks; clew[j + 1] = kl;
    }
}

// ---------------- fp32 GEMM v2: tile 64x128, KT=16, fused qa ----------------
// Grid 782/391 blocks (was 392/196) -> whole grid co-resident on 256 CUs.
__global__ __launch_bounds__(256) void k_gemm(const float* __restrict__ X,
                                              const float* __restrict__ W,
                                              float* __restrict__ C,
                                              int N, int K, int M,
                                              const float* __restrict__ avec,
                                              float* __restrict__ qaOut,
                                              int H, int F) {
    __shared__ float Xs[16][68];
    __shared__ float Ws[16][132];
    __shared__ float qred[64][17];
    int r0 = blockIdx.y * 64;
    int c0 = blockIdx.x * 128;
    int t = threadIdx.x;
    int ty = t >> 4, tx = t & 15;   // rows ty*4..+3, cols tx*8..+7

    float acc[4][8];
#pragma unroll
    for (int i = 0; i < 4; i++)
#pragma unroll
        for (int j = 0; j < 8; j++) acc[i][j] = 0.f;

    int lr = t >> 2;            // X row 0..63
    int lk = (t & 3) * 4;       // k offset 0,4,8,12
    bool xok = (r0 + lr) < N;
    const float* Xp = X + (size_t)(r0 + lr) * K + lk;
    int wr = t >> 1;            // W row 0..127
    int wk = (t & 1) * 8;       // k offset 0,8
    const float* Wp = W + (size_t)(c0 + wr) * K + wk;

    for (int k0 = 0; k0 < K; k0 += 16) {
        float4 xv = xok ? *(const float4*)(Xp + k0) : make_float4(0.f, 0.f, 0.f, 0.f);
        float4 wv0 = *(const float4*)(Wp + k0);
        float4 wv1 = *(const float4*)(Wp + k0 + 4);
        __syncthreads();
        Xs[lk + 0][lr] = xv.x; Xs[lk + 1][lr] = xv.y;
        Xs[lk + 2][lr] = xv.z; Xs[lk + 3][lr] = xv.w;
        Ws[wk + 0][wr] = wv0.x; Ws[wk + 1][wr] = wv0.y;
        Ws[wk + 2][wr] = wv0.z; Ws[wk + 3][wr] = wv0.w;
        Ws[wk + 4][wr] = wv1.x; Ws[wk + 5][wr] = wv1.y;
        Ws[wk + 6][wr] = wv1.z; Ws[wk + 7][wr] = wv1.w;
        __syncthreads();
#pragma unroll
        for (int k = 0; k < 16; k++) {
            float4 a = *(const float4*)&Xs[k][ty * 4];
            float4 b0 = *(const float4*)&Ws[k][tx * 8];
            float4 b1 = *(const float4*)&Ws[k][tx * 8 + 4];
            float av[4] = {a.x, a.y, a.z, a.w};
            float bv[8] = {b0.x, b0.y, b0.z, b0.w, b1.x, b1.y, b1.z, b1.w};
#pragma unroll
            for (int i = 0; i < 4; i++)
#pragma unroll
                for (int j = 0; j < 8; j++) acc[i][j] += av[i] * bv[j];
        }
    }

#pragma unroll
    for (int i = 0; i < 4; i++) {
        int row = r0 + ty * 4 + i;
        if (row < N) {
            float4 v0 = make_float4(acc[i][0], acc[i][1], acc[i][2], acc[i][3]);
            float4 v1 = make_float4(acc[i][4], acc[i][5], acc[i][6], acc[i][7]);
            *(float4*)&C[(size_t)row * M + c0 + tx * 8] = v0;
            *(float4*)&C[(size_t)row * M + c0 + tx * 8 + 4] = v1;
        }
    }

    if (qaOut) {
        int f0 = (c0 + tx * 8) & (F - 1);
        float4 a0 = *(const float4*)&avec[f0];
        float4 a1 = *(const float4*)&avec[f0 + 4];
#pragma unroll
        for (int i = 0; i < 4; i++) {
            float s = acc[i][0] * a0.x + acc[i][1] * a0.y + acc[i][2] * a0.z + acc[i][3] * a0.w
                    + acc[i][4] * a1.x + acc[i][5] * a1.y + acc[i][6] * a1.z + acc[i][7] * a1.w;
            qred[ty * 4 + i][tx] = s;
        }
        __syncthreads();
        if (t < 64) {
            int R = r0 + t;
            if (R < N) {
                float s0 = 0.f, s1 = 0.f;
#pragma unroll
                for (int x = 0; x < 8; x++) { s0 += qred[t][x]; s1 += qred[t][x + 8]; }
                if (F == 64) {
                    int hb = c0 >> 6;
                    qaOut[(size_t)R * H + hb] = s0;
                    qaOut[(size_t)R * H + hb + 1] = s1;
                } else {
                    qaOut[R] = s0 + s1;
                }
            }
        }
    }
}

// ---------------- fused softmax-stats + aggregation v2: wave per node ----------------
template <int H, int F, int VW, bool LOUT>
__global__ __launch_bounds__(256) void k_fagg(const float* __restrict__ feat,
                                              const float* __restrict__ qa,
                                              const float* __restrict__ bias,
                                              const int* __restrict__ rowptr,
                                              const int* __restrict__ csr_src,
                                              const float* __restrict__ csr_lew,
                                              float* __restrict__ out, int N) {
    constexpr int M = H * F;
    constexpr int CACHE = 128;
    constexpr int EPP = 64 / H;   // edges per score pass
    __shared__ int sh_src[4][CACHE];
    __shared__ float sh_sc[4][CACHE * H];
    int w = threadIdx.x >> 6, l = threadIdx.x & 63;
    int n = blockIdx.x * 4 + w;
    if (n >= N) return;
    int beg = rowptr[n];
    int deg = rowptr[n + 1] - beg;
    int c = l * VW;
    const int hh = c / F;

    float acc0[VW], acc1[VW];
#pragma unroll
    for (int j = 0; j < VW; j++) { acc0[j] = 0.f; acc1[j] = 0.f; }

    if (deg > 0) {
        if (deg <= CACHE) {
            const int e0 = l / H;
            const int h = l & (H - 1);
            float qd = qa[(size_t)n * H + h];
            float mx = -1e30f;
            for (int i0 = 0; i0 < deg; i0 += EPP) {
                int e = i0 + e0;
                if (e < deg) {
                    int src = csr_src[beg + e];
                    float lw = csr_lew[beg + e];
                    if (h == 0) sh_src[w][e] = src;
                    float sc = leaky01(qa[(size_t)src * H + h] + qd + lw);
                    sh_sc[w][e * H + h] = sc;
                    mx = fmaxf(mx, sc);
                }
            }
            for (int off = 32; off >= H; off >>= 1)
                mx = fmaxf(mx, __shfl_xor(mx, off, 64));
            float sm = 0.f;
            for (int i0 = 0; i0 < deg; i0 += EPP) {
                int e = i0 + e0;
                if (e < deg) sm += __expf(sh_sc[w][e * H + h] - mx);
            }
            for (int off = 32; off >= H; off >>= 1)
                sm += __shfl_xor(sm, off, 64);
            float inv = 1.f / fmaxf(sm, 1e-20f);
            for (int i0 = 0; i0 < deg; i0 += EPP) {
                int e = i0 + e0;
                if (e < deg)
                    sh_sc[w][e * H + h] = __expf(sh_sc[w][e * H + h] - mx) * inv;
            }
            int i = 0;
            for (; i + 4 <= deg; i += 4) {
                int s0 = sh_src[w][i], s1 = sh_src[w][i + 1];
                int s2 = sh_src[w][i + 2], s3 = sh_src[w][i + 3];
                float a0 = sh_sc[w][i * H + hh], a1 = sh_sc[w][(i + 1) * H + hh];
                float a2 = sh_sc[w][(i + 2) * H + hh], a3 = sh_sc[w][(i + 3) * H + hh];
                float f0[VW], f1[VW], f2[VW], f3[VW];
                if (VW == 4) {
                    float4 v0 = *(const float4*)&feat[(size_t)s0 * M + c];
                    float4 v1 = *(const float4*)&feat[(size_t)s1 * M + c];
                    float4 v2 = *(const float4*)&feat[(size_t)s2 * M + c];
                    float4 v3 = *(const float4*)&feat[(size_t)s3 * M + c];
                    f0[0] = v0.x; f0[1] = v0.y; f0[2] = v0.z; f0[3] = v0.w;
                    f1[0] = v1.x; f1[1] = v1.y; f1[2] = v1.z; f1[3] = v1.w;
                    f2[0] = v2.x; f2[1] = v2.y; f2[2] = v2.z; f2[3] = v2.w;
                    f3[0] = v3.x; f3[1] = v3.y; f3[2] = v3.z; f3[3] = v3.w;
                } else {
                    float2 v0 = *(const float2*)&feat[(size_t)s0 * M + c];
                    float2 v1 = *(const float2*)&feat[(size_t)s1 * M + c];
                    float2 v2 = *(const float2*)&feat[(size_t)s2 * M + c];
                    float2 v3 = *(const float2*)&feat[(size_t)s3 * M + c];
                    f0[0] = v0.x; f0[1] = v0.y;
                    f1[0] = v1.x; f1[1] = v1.y;
                    f2[0] = v2.x; f2[1] = v2.y;
                    f3[0] = v3.x; f3[1] = v3.y;
                }
#pragma unroll
                for (int j = 0; j < VW; j++) {
                    acc0[j] += a0 * f0[j] + a1 * f1[j];
                    acc1[j] += a2 * f2[j] + a3 * f3[j];
                }
            }
            for (; i < deg; ++i) {
                int s0 = sh_src[w][i];
                float a0 = sh_sc[w][i * H + hh];
                if (VW == 4) {
                    float4 v0 = *(const float4*)&feat[(size_t)s0 * M + c];
                    acc0[0] += a0 * v0.x; acc0[1] += a0 * v0.y;
                    acc0[2] += a0 * v0.z; acc0[3] += a0 * v0.w;
                } else {
                    float2 v0 = *(const float2*)&feat[(size_t)s0 * M + c];
                    acc0[0] += a0 * v0.x; acc0[1] += a0 * v0.y;
                }
            }
        } else {
            float qd[H];
#pragma unroll
            for (int h = 0; h < H; h++) qd[h] = qa[(size_t)n * H + h];
            int end = beg + deg;
            float mx[H];
#pragma unroll
            for (int h = 0; h < H; h++) mx[h] = -1e30f;
            for (int i = beg + l; i < end; i += 64) {
                int src = csr_src[i];
                float lw = csr_lew[i];
#pragma unroll
                for (int h = 0; h < H; h++)
                    mx[h] = fmaxf(mx[h], leaky01(qa[(size_t)src * H + h] + qd[h] + lw));
            }
#pragma unroll
            for (int h = 0; h < H; h++) {
                for (int off = 32; off > 0; off >>= 1)
                    mx[h] = fmaxf(mx[h], __shfl_xor(mx[h], off, 64));
            }
            float sm[H];
#pragma unroll
            for (int h = 0; h < H; h++) sm[h] = 0.f;
            for (int i = beg + l; i < end; i += 64) {
                int src = csr_src[i];
                float lw = csr_lew[i];
#pragma unroll
                for (int h = 0; h < H; h++)
                    sm[h] += __expf(leaky01(qa[(size_t)src * H + h] + qd[h] + lw) - mx[h]);
            }
#pragma unroll
            for (int h = 0; h < H; h++) {
                for (int off = 32; off > 0; off >>= 1)
                    sm[h] += __shfl_xor(sm[h], off, 64);
            }
            float inv[H];
#pragma unroll
            for (int h = 0; h < H; h++) inv[h] = 1.f / fmaxf(sm[h], 1e-20f);

            for (int c0 = 0; c0 < deg; c0 += 64) {
                int cn = min(64, deg - c0);
                if (l < cn) {
                    int src = csr_src[beg + c0 + l];
                    float lw = csr_lew[beg + c0 + l];
                    sh_src[w][l] = src;
#pragma unroll
                    for (int h = 0; h < H; h++)
                        sh_sc[w][l * H + h] =
                            __expf(leaky01(qa[(size_t)src * H + h] + qd[h] + lw) - mx[h]) * inv[h];
                }
                for (int i = 0; i < cn; i++) {
                    int s0 = sh_src[w][i];
                    float a0 = sh_sc[w][i * H + hh];
                    if (VW == 4) {
                        float4 v0 = *(const float4*)&feat[(size_t)s0 * M + c];
                        acc0[0] += a0 * v0.x; acc0[1] += a0 * v0.y;
                        acc0[2] += a0 * v0.z; acc0[3] += a0 * v0.w;
                    } else {
                        float2 v0 = *(const float2*)&feat[(size_t)s0 * M + c];
                        acc0[0] += a0 * v0.x; acc0[1] += a0 * v0.y;
                    }
                }
            }
        }
    }

#pragma unroll
    for (int j = 0; j < VW; j++) {
        float r = acc0[j] + acc1[j] + bias[c + j];
        if (LOUT) r = leaky01(r);
        out[(size_t)n * M + c + j] = r;
    }
}

// ---------------- fused predictor v8 (R8-proven): 256 threads / 128 pairs ----------------
__global__ __launch_bounds__(256) void k_predf6(const float* __restrict__ h2,
                                                const int* __restrict__ ps, const int* __restrict__ pd,
                                                const int* __restrict__ ns, const int* __restrict__ nd,
                                                const float* __restrict__ W1, const float* __restrict__ b1,
                                                const float* __restrict__ W2, const float* __restrict__ b2,
                                                const float* __restrict__ W3, const float* __restrict__ b3,
                                                float* __restrict__ out, int npos, int ntot) {
    __shared__ float Zs[128 * 36];   // Z chunk [pair][36]; reused as T1-half [pair][32+pad]
    __shared__ float Wc[32 * 68];    // W1 chunk [k][out]
    __shared__ int sp[128], dp[128];

    int t = threadIdx.x;
    int p0 = blockIdx.x * 128;
    int ty2 = t >> 3;       // 0..31 pair groups: pairs ty2 + 32*i, i<4
    int tx2 = t & 7;        // 0..7 out groups: outs tx2*8..+7

    if (t < 128) {
        int pr = p0 + t;
        int s = 0, d = 0;
        if (pr < ntot) {
            if (pr < npos) { s = ps[pr]; d = pd[pr]; }
            else           { s = ns[pr - npos]; d = nd[pr - npos]; }
        }
        sp[t] = s; dp[t] = d;
    }
    __syncthreads();

    float acc[4][8];
#pragma unroll
    for (int i = 0; i < 4; i++)
#pragma unroll
        for (int j = 0; j < 8; j++) acc[i][j] = 0.f;

    int sr = t >> 3;        // staging row within sweep (0..31)
    int sq = t & 7;         // staging quad (0..7)

    for (int kc = 0; kc < 128; kc += 32) {
        // stage Z chunk: 4 sweeps x 32 rows, 8 threads/row (float4 each)
#pragma unroll
        for (int it = 0; it < 4; ++it) {
            int r = it * 32 + sr;
            int s = sp[r], d = dp[r];
            float4 a = *(const float4*)&h2[(size_t)s * 128 + kc + sq * 4];
            float4 b = *(const float4*)&h2[(size_t)d * 128 + kc + sq * 4];
            *(float4*)&Zs[r * 36 + sq * 4] =
                make_float4(a.x * b.x, a.y * b.y, a.z * b.z, a.w * b.w);
        }
        // stage W1 chunk [32 k][64 outs]
        {
            int out_ = t & 63;
            int kh = (t >> 6) * 8;
            const float* wr = W1 + (size_t)out_ * 128 + kc + kh;
#pragma unroll
            for (int c = 0; c < 2; c++) {
                float4 wv = *(const float4*)(wr + c * 4);
                Wc[(kh + c * 4 + 0) * 68 + out_] = wv.x;
                Wc[(kh + c * 4 + 1) * 68 + out_] = wv.y;
                Wc[(kh + c * 4 + 2) * 68 + out_] = wv.z;
                Wc[(kh + c * 4 + 3) * 68 + out_] = wv.w;
            }
        }
        __syncthreads();
#pragma unroll
        for (int k4 = 0; k4 < 8; ++k4) {
            float4 a4[4];
#pragma unroll
            for (int i = 0; i < 4; i++)
                a4[i] = *(const float4*)&Zs[(ty2 + 32 * i) * 36 + k4 * 4];
#pragma unroll
            for (int kk = 0; kk < 4; ++kk) {
                float4 bA = *(const float4*)&Wc[(k4 * 4 + kk) * 68 + tx2 * 8];
                float4 bB = *(const float4*)&Wc[(k4 * 4 + kk) * 68 + tx2 * 8 + 4];
                float bv[8] = {bA.x, bA.y, bA.z, bA.w, bB.x, bB.y, bB.z, bB.w};
#pragma unroll
                for (int i = 0; i < 4; i++) {
                    float a = (kk == 0) ? a4[i].x : (kk == 1) ? a4[i].y : (kk == 2) ? a4[i].z : a4[i].w;
#pragma unroll
                    for (int j = 0; j < 8; j++) acc[i][j] += a * bv[j];
                }
            }
        }
        __syncthreads();
    }

    // bias (pre-activation kept in acc)
    {
        float4 b1a = *(const float4*)&b1[tx2 * 8];
        float4 b1b = *(const float4*)&b1[tx2 * 8 + 4];
        float bb[8] = {b1a.x, b1a.y, b1a.z, b1a.w, b1b.x, b1b.y, b1b.z, b1b.w};
#pragma unroll
        for (int i = 0; i < 4; i++)
#pragma unroll
            for (int j = 0; j < 8; j++) acc[i][j] += bb[j];
    }

    float t2[32];
#pragma unroll
    for (int o = 0; o < 32; o++) t2[o] = b2[o];

    // ---- half A: outs 0..31 (written by tx2 0..3) ----
    if (tx2 < 4) {
#pragma unroll
        for (int i = 0; i < 4; i++) {
            int row = ty2 + 32 * i;
            *(float4*)&Zs[row * 36 + tx2 * 8] =
                make_float4(acc[i][0], acc[i][1], acc[i][2], acc[i][3]);
            *(float4*)&Zs[row * 36 + tx2 * 8 + 4] =
                make_float4(acc[i][4], acc[i][5], acc[i][6], acc[i][7]);
        }
    }
    __syncthreads();
    if (t < 128) {
        for (int j = 0; j < 32; j += 4) {
            float4 v4 = *(const float4*)&Zs[t * 36 + j];
            float v0 = leaky02(v4.x), v1 = leaky02(v4.y), v2 = leaky02(v4.z), v3 = leaky02(v4.w);
#pragma unroll
            for (int o = 0; o < 32; o++) {
                const float* w2 = W2 + (size_t)o * 64 + j;
                t2[o] += v0 * w2[0] + v1 * w2[1] + v2 * w2[2] + v3 * w2[3];
            }
        }
    }
    __syncthreads();
    // ---- half B: outs 32..63 (written by tx2 4..7) ----
    if (tx2 >= 4) {
#pragma unroll
        for (int i = 0; i < 4; i++) {
            int row = ty2 + 32 * i;
            *(float4*)&Zs[row * 36 + (tx2 - 4) * 8] =
                make_float4(acc[i][0], acc[i][1], acc[i][2], acc[i][3]);
            *(float4*)&Zs[row * 36 + (tx2 - 4) * 8 + 4] =
                make_float4(acc[i][4], acc[i][5], acc[i][6], acc[i][7]);
        }
    }
    __syncthreads();
    if (t < 128) {
        for (int j = 0; j < 32; j += 4) {
            float4 v4 = *(const float4*)&Zs[t * 36 + j];
            float v0 = leaky02(v4.x), v1 = leaky02(v4.y), v2 = leaky02(v4.z), v3 = leaky02(v4.w);
#pragma unroll
            for (int o = 0; o < 32; o++) {
                const float* w2 = W2 + (size_t)o * 64 + 32 + j;
                t2[o] += v0 * w2[0] + v1 * w2[1] + v2 * w2[2] + v3 * w2[3];
            }
        }
        float o3 = b3[0];
#pragma unroll
        for (int o = 0; o < 32; o++) o3 += leaky02(t2[o]) * W3[o];
        if (p0 + t < ntot) out[p0 + t] = o3;
    }
}

extern "C" void kernel_launch(void* const* d_in, const int* in_sizes, int n_in,
                              void* d_out, int out_size, void* d_ws, size_t ws_size,
                              hipStream_t stream) {
    const float* x    = (const float*)d_in[0];
    const float* ew   = (const float*)d_in[1];
    const int* esrc   = (const int*)d_in[2];
    const int* edst   = (const int*)d_in[3];
    const int* pos_s  = (const int*)d_in[4];
    const int* pos_d  = (const int*)d_in[5];
    const int* neg_s  = (const int*)d_in[6];
    const int* neg_d  = (const int*)d_in[7];
    const float* W0 = (const float*)d_in[8];
    const float* a0 = (const float*)d_in[9];
    const float* b0 = (const float*)d_in[10];
    const float* W1 = (const float*)d_in[11];
    const float* a1 = (const float*)d_in[12];
    const float* b1 = (const float*)d_in[13];
    const float* W2 = (const float*)d_in[14];
    const float* a2 = (const float*)d_in[15];
    const float* b2 = (const float*)d_in[16];
    const float* pW1 = (const float*)d_in[17];
    const float* pb1 = (const float*)d_in[18];
    const float* pW2 = (const float*)d_in[19];
    const float* pb2 = (const float*)d_in[20];
    const float* pW3 = (const float*)d_in[21];
    const float* pb3 = (const float*)d_in[22];

    const int N = in_sizes[0] / N_IN;   // 25000
    const int E = in_sizes[1];          // 400000
    const int NP = in_sizes[4];         // 100000

    size_t off = 0;
    auto alloc = [&](size_t bytes) {
        void* p = (char*)d_ws + off;
        off += (bytes + 255) & ~(size_t)255;
        return p;
    };
    int* deg      = (int*)alloc((size_t)N * 4);
    int* cursor   = (int*)alloc((size_t)N * 4);
    int* rowptr   = (int*)alloc((size_t)(N + 1) * 4);
    int* bsum     = (int*)alloc(512);
    int* boff     = (int*)alloc(512);
    int* csr_eid  = (int*)alloc((size_t)E * 4);
    int* csr_src  = (int*)alloc((size_t)E * 4);
    float* csr_lew = (float*)alloc((size_t)E * 4);
    float* qa     = (float*)alloc((size_t)N * 4 * 4);
    float* A      = (float*)alloc((size_t)N * 256 * 4);
    float* B      = (float*)alloc((size_t)N * 256 * 4);
    (void)ws_size; (void)n_in; (void)out_size;

    float* out_pred = (float*)d_out;              // [200000]
    float* emb      = (float*)d_out + 2 * NP;     // [25000 x 128]

    hipMemsetAsync(deg, 0, (size_t)N * 4, stream);
    hipMemsetAsync(cursor, 0, (size_t)N * 4, stream);

    int eb = (E + 255) / 256;
    int nb = (N + 255) / 256;   // 98
    k_count<<<eb, 256, 0, stream>>>(edst, deg, E);
    k_scan1<<<nb, 256, 0, stream>>>(deg, rowptr, bsum, N);
    k_scan2<<<1, 128, 0, stream>>>(bsum, boff, nb);
    k_scan3<<<nb, 256, 0, stream>>>(rowptr, boff, N);
    k_fill<<<eb, 256, 0, stream>>>(esrc, edst, ew, rowptr, cursor, csr_eid, csr_src, csr_lew, E);
    k_sortseg<<<(N + 255) / 256, 256, 0, stream>>>(rowptr, csr_eid, csr_src, csr_lew, N);

    int rb = (N + 63) / 64;     // 391 row blocks
    int sb = (N + 3) / 4;       // wave-per-node blocks

    // layer 0: K=128, M=256
    k_gemm<<<dim3(2, rb), 256, 0, stream>>>(x, W0, A, N, 128, 256, a0, qa, 4, 64);
    k_fagg<4, 64, 4, true><<<sb, 256, 0, stream>>>(A, qa, b0, rowptr, csr_src, csr_lew, B, N);

    // layer 1: K=256, M=256
    k_gemm<<<dim3(2, rb), 256, 0, stream>>>(B, W1, A, N, 256, 256, a1, qa, 4, 64);
    k_fagg<4, 64, 4, true><<<sb, 256, 0, stream>>>(A, qa, b1, rowptr, csr_src, csr_lew, B, N);

    // layer 2: K=256, M=128
    k_gemm<<<dim3(1, rb), 256, 0, stream>>>(B, W2, A, N, 256, 128, a2, qa, 1, 128);
    k_fagg<1, 128, 2, false><<<sb, 256, 0, stream>>>(A, qa, b2, rowptr, csr_src, csr_lew, emb, N);

    // fused predictor on 2*NP pairs
    int ntot = 2 * NP;
    k_predf6<<<(ntot + 127) / 128, 256, 0, stream>>>(emb, pos_s, pos_d, neg_s, neg_d,
                                                     pW1, pb1, pW2, pb2, pW3, pb3,
                                                     out_pred, NP, ntot);
}

// Round 14
// 439.987 us; speedup vs baseline: 1.7370x; 1.1086x over previous
//
#include <hip/hip_runtime.h>
#include <math.h>
#include <limits.h>

#define N_IN 128

__device__ __forceinline__ float leaky01(float x) { return x >= 0.f ? x : 0.01f * x; }
__device__ __forceinline__ float leaky02(float x) { return x >= 0.f ? x : 0.2f * x; }

// ---------------- CSR build ----------------
__global__ void k_count(const int* __restrict__ edst, int* __restrict__ deg, int E) {
    int e = blockIdx.x * 256 + threadIdx.x;
    if (e < E) atomicAdd(&deg[edst[e]], 1);
}

__global__ void k_scan1(const int* __restrict__ deg, int* __restrict__ rowptr,
                        int* __restrict__ bsum, int n) {
    __shared__ int s[256];
    int b = blockIdx.x, t = threadIdx.x;
    int idx = b * 256 + t;
    int v = (idx < n) ? deg[idx] : 0;
    s[t] = v;
    __syncthreads();
    for (int off = 1; off < 256; off <<= 1) {
        int x = (t >= off) ? s[t - off] : 0;
        __syncthreads();
        s[t] += x;
        __syncthreads();
    }
    if (idx < n) rowptr[idx + 1] = s[t];
    if (t == 255) bsum[b] = s[255];
}

__global__ void k_scan2(const int* __restrict__ bsum, int* __restrict__ boff, int nb) {
    __shared__ int s[128];
    int t = threadIdx.x;
    int v = (t < nb) ? bsum[t] : 0;
    s[t] = v;
    __syncthreads();
    for (int off = 1; off < 128; off <<= 1) {
        int x = (t >= off) ? s[t - off] : 0;
        __syncthreads();
        s[t] += x;
        __syncthreads();
    }
    if (t < nb) boff[t] = s[t] - v;   // exclusive
}

__global__ void k_scan3(int* __restrict__ rowptr, const int* __restrict__ boff, int n) {
    int idx = blockIdx.x * 256 + threadIdx.x;
    if (idx < n) rowptr[idx + 1] += boff[idx >> 8];
    if (idx == 0) rowptr[0] = 0;
}

__global__ void k_fill(const int* __restrict__ esrc, const int* __restrict__ edst,
                       const float* __restrict__ ew, const int* __restrict__ rowptr,
                       int* __restrict__ cursor, int* __restrict__ eid,
                       int* __restrict__ csrc, float* __restrict__ clew, int E) {
    int e = blockIdx.x * 256 + threadIdx.x;
    if (e >= E) return;
    int d = edst[e];
    int slot = rowptr[d] + atomicAdd(&cursor[d], 1);
    eid[slot] = e;
    csrc[slot] = esrc[e];
    clew[slot] = log1pf(ew[e]);
}

// wave-parallel deterministic segment sort: one wave per node.
// deg<=64: whole segment in wave registers, rank via shfl-compare (eids unique),
// scatter back -> no dependent global chains. Serial fallback for deg>64 (rare).
__global__ __launch_bounds__(256) void k_sortw(const int* __restrict__ rowptr,
                                               int* __restrict__ eid,
                                               int* __restrict__ csrc,
                                               float* __restrict__ clew, int n) {
    int w = threadIdx.x >> 6, l = threadIdx.x & 63;
    int v = blockIdx.x * 4 + w;
    if (v >= n) return;
    int b = rowptr[v], e = rowptr[v + 1];
    int deg = e - b;
    if (deg <= 1) return;
    if (deg <= 64) {
        int my_eid = INT_MAX, my_src = 0;
        float my_lew = 0.f;
        if (l < deg) {
            my_eid = eid[b + l];
            my_src = csrc[b + l];
            my_lew = clew[b + l];
        }
        int rank = 0;
        for (int j = 0; j < 64; j++) {
            int ej = __shfl(my_eid, j, 64);
            rank += (ej < my_eid) ? 1 : 0;
        }
        if (l < deg) {
            eid[b + rank] = my_eid;
            csrc[b + rank] = my_src;
            clew[b + rank] = my_lew;
        }
    } else if (l == 0) {
        for (int i = b + 1; i < e; i++) {
            int ke = eid[i], ks = csrc[i];
            float kl = clew[i];
            int j = i - 1;
            while (j >= b && eid[j] > ke) {
                eid[j + 1] = eid[j]; csrc[j + 1] = csrc[j]; clew[j + 1] = clew[j];
                j--;
            }
            eid[j + 1] = ke; csrc[j + 1] = ks; clew[j + 1] = kl;
        }
    }
}

// ---------------- fp32 GEMM v2: tile 64x128, KT=16, fused qa ----------------
__global__ __launch_bounds__(256) void k_gemm(const float* __restrict__ X,
                                              const float* __restrict__ W,
                                              float* __restrict__ C,
                                              int N, int K, int M,
                                              const float* __restrict__ avec,
                                              float* __restrict__ qaOut,
                                              int H, int F) {
    __shared__ float Xs[16][68];
    __shared__ float Ws[16][132];
    __shared__ float qred[64][17];
    int r0 = blockIdx.y * 64;
    int c0 = blockIdx.x * 128;
    int t = threadIdx.x;
    int ty = t >> 4, tx = t & 15;   // rows ty*4..+3, cols tx*8..+7

    float acc[4][8];
#pragma unroll
    for (int i = 0; i < 4; i++)
#pragma unroll
        for (int j = 0; j < 8; j++) acc[i][j] = 0.f;

    int lr = t >> 2;            // X row 0..63
    int lk = (t & 3) * 4;       // k offset 0,4,8,12
    bool xok = (r0 + lr) < N;
    const float* Xp = X + (size_t)(r0 + lr) * K + lk;
    int wr = t >> 1;            // W row 0..127
    int wk = (t & 1) * 8;       // k offset 0,8
    const float* Wp = W + (size_t)(c0 + wr) * K + wk;

    for (int k0 = 0; k0 < K; k0 += 16) {
        float4 xv = xok ? *(const float4*)(Xp + k0) : make_float4(0.f, 0.f, 0.f, 0.f);
        float4 wv0 = *(const float4*)(Wp + k0);
        float4 wv1 = *(const float4*)(Wp + k0 + 4);
        __syncthreads();
        Xs[lk + 0][lr] = xv.x; Xs[lk + 1][lr] = xv.y;
        Xs[lk + 2][lr] = xv.z; Xs[lk + 3][lr] = xv.w;
        Ws[wk + 0][wr] = wv0.x; Ws[wk + 1][wr] = wv0.y;
        Ws[wk + 2][wr] = wv0.z; Ws[wk + 3][wr] = wv0.w;
        Ws[wk + 4][wr] = wv1.x; Ws[wk + 5][wr] = wv1.y;
        Ws[wk + 6][wr] = wv1.z; Ws[wk + 7][wr] = wv1.w;
        __syncthreads();
#pragma unroll
        for (int k = 0; k < 16; k++) {
            float4 a = *(const float4*)&Xs[k][ty * 4];
            float4 b0 = *(const float4*)&Ws[k][tx * 8];
            float4 b1 = *(const float4*)&Ws[k][tx * 8 + 4];
            float av[4] = {a.x, a.y, a.z, a.w};
            float bv[8] = {b0.x, b0.y, b0.z, b0.w, b1.x, b1.y, b1.z, b1.w};
#pragma unroll
            for (int i = 0; i < 4; i++)
#pragma unroll
                for (int j = 0; j < 8; j++) acc[i][j] += av[i] * bv[j];
        }
    }

#pragma unroll
    for (int i = 0; i < 4; i++) {
        int row = r0 + ty * 4 + i;
        if (row < N) {
            float4 v0 = make_float4(acc[i][0], acc[i][1], acc[i][2], acc[i][3]);
            float4 v1 = make_float4(acc[i][4], acc[i][5], acc[i][6], acc[i][7]);
            *(float4*)&C[(size_t)row * M + c0 + tx * 8] = v0;
            *(float4*)&C[(size_t)row * M + c0 + tx * 8 + 4] = v1;
        }
    }

    if (qaOut) {
        int f0 = (c0 + tx * 8) & (F - 1);
        float4 a0 = *(const float4*)&avec[f0];
        float4 a1 = *(const float4*)&avec[f0 + 4];
#pragma unroll
        for (int i = 0; i < 4; i++) {
            float s = acc[i][0] * a0.x + acc[i][1] * a0.y + acc[i][2] * a0.z + acc[i][3] * a0.w
                    + acc[i][4] * a1.x + acc[i][5] * a1.y + acc[i][6] * a1.z + acc[i][7] * a1.w;
            qred[ty * 4 + i][tx] = s;
        }
        __syncthreads();
        if (t < 64) {
            int R = r0 + t;
            if (R < N) {
                float s0 = 0.f, s1 = 0.f;
#pragma unroll
                for (int x = 0; x < 8; x++) { s0 += qred[t][x]; s1 += qred[t][x + 8]; }
                if (F == 64) {
                    int hb = c0 >> 6;
                    qaOut[(size_t)R * H + hb] = s0;
                    qaOut[(size_t)R * H + hb + 1] = s1;
                } else {
                    qaOut[R] = s0 + s1;
                }
            }
        }
    }
}

// ---------------- fused softmax-stats + aggregation v2: wave per node ----------------
template <int H, int F, int VW, bool LOUT>
__global__ __launch_bounds__(256) void k_fagg(const float* __restrict__ feat,
                                              const float* __restrict__ qa,
                                              const float* __restrict__ bias,
                                              const int* __restrict__ rowptr,
                                              const int* __restrict__ csr_src,
                                              const float* __restrict__ csr_lew,
                                              float* __restrict__ out, int N) {
    constexpr int M = H * F;
    constexpr int CACHE = 128;
    constexpr int EPP = 64 / H;   // edges per score pass
    __shared__ int sh_src[4][CACHE];
    __shared__ float sh_sc[4][CACHE * H];
    int w = threadIdx.x >> 6, l = threadIdx.x & 63;
    int n = blockIdx.x * 4 + w;
    if (n >= N) return;
    int beg = rowptr[n];
    int deg = rowptr[n + 1] - beg;
    int c = l * VW;
    const int hh = c / F;

    float acc0[VW], acc1[VW];
#pragma unroll
    for (int j = 0; j < VW; j++) { acc0[j] = 0.f; acc1[j] = 0.f; }

    if (deg > 0) {
        if (deg <= CACHE) {
            const int e0 = l / H;
            const int h = l & (H - 1);
            float qd = qa[(size_t)n * H + h];
            float mx = -1e30f;
            for (int i0 = 0; i0 < deg; i0 += EPP) {
                int e = i0 + e0;
                if (e < deg) {
                    int src = csr_src[beg + e];
                    float lw = csr_lew[beg + e];
                    if (h == 0) sh_src[w][e] = src;
                    float sc = leaky01(qa[(size_t)src * H + h] + qd + lw);
                    sh_sc[w][e * H + h] = sc;
                    mx = fmaxf(mx, sc);
                }
            }
            for (int off = 32; off >= H; off >>= 1)
                mx = fmaxf(mx, __shfl_xor(mx, off, 64));
            float sm = 0.f;
            for (int i0 = 0; i0 < deg; i0 += EPP) {
                int e = i0 + e0;
                if (e < deg) sm += __expf(sh_sc[w][e * H + h] - mx);
            }
            for (int off = 32; off >= H; off >>= 1)
                sm += __shfl_xor(sm, off, 64);
            float inv = 1.f / fmaxf(sm, 1e-20f);
            for (int i0 = 0; i0 < deg; i0 += EPP) {
                int e = i0 + e0;
                if (e < deg)
                    sh_sc[w][e * H + h] = __expf(sh_sc[w][e * H + h] - mx) * inv;
            }
            int i = 0;
            for (; i + 4 <= deg; i += 4) {
                int s0 = sh_src[w][i], s1 = sh_src[w][i + 1];
                int s2 = sh_src[w][i + 2], s3 = sh_src[w][i + 3];
                float a0 = sh_sc[w][i * H + hh], a1 = sh_sc[w][(i + 1) * H + hh];
                float a2 = sh_sc[w][(i + 2) * H + hh], a3 = sh_sc[w][(i + 3) * H + hh];
                float f0[VW], f1[VW], f2[VW], f3[VW];
                if (VW == 4) {
                    float4 v0 = *(const float4*)&feat[(size_t)s0 * M + c];
                    float4 v1 = *(const float4*)&feat[(size_t)s1 * M + c];
                    float4 v2 = *(const float4*)&feat[(size_t)s2 * M + c];
                    float4 v3 = *(const float4*)&feat[(size_t)s3 * M + c];
                    f0[0] = v0.x; f0[1] = v0.y; f0[2] = v0.z; f0[3] = v0.w;
                    f1[0] = v1.x; f1[1] = v1.y; f1[2] = v1.z; f1[3] = v1.w;
                    f2[0] = v2.x; f2[1] = v2.y; f2[2] = v2.z; f2[3] = v2.w;
                    f3[0] = v3.x; f3[1] = v3.y; f3[2] = v3.z; f3[3] = v3.w;
                } else {
                    float2 v0 = *(const float2*)&feat[(size_t)s0 * M + c];
                    float2 v1 = *(const float2*)&feat[(size_t)s1 * M + c];
                    float2 v2 = *(const float2*)&feat[(size_t)s2 * M + c];
                    float2 v3 = *(const float2*)&feat[(size_t)s3 * M + c];
                    f0[0] = v0.x; f0[1] = v0.y;
                    f1[0] = v1.x; f1[1] = v1.y;
                    f2[0] = v2.x; f2[1] = v2.y;
                    f3[0] = v3.x; f3[1] = v3.y;
                }
#pragma unroll
                for (int j = 0; j < VW; j++) {
                    acc0[j] += a0 * f0[j] + a1 * f1[j];
                    acc1[j] += a2 * f2[j] + a3 * f3[j];
                }
            }
            for (; i < deg; ++i) {
                int s0 = sh_src[w][i];
                float a0 = sh_sc[w][i * H + hh];
                if (VW == 4) {
                    float4 v0 = *(const float4*)&feat[(size_t)s0 * M + c];
                    acc0[0] += a0 * v0.x; acc0[1] += a0 * v0.y;
                    acc0[2] += a0 * v0.z; acc0[3] += a0 * v0.w;
                } else {
                    float2 v0 = *(const float2*)&feat[(size_t)s0 * M + c];
                    acc0[0] += a0 * v0.x; acc0[1] += a0 * v0.y;
                }
            }
        } else {
            float qd[H];
#pragma unroll
            for (int h = 0; h < H; h++) qd[h] = qa[(size_t)n * H + h];
            int end = beg + deg;
            float mx[H];
#pragma unroll
            for (int h = 0; h < H; h++) mx[h] = -1e30f;
            for (int i = beg + l; i < end; i += 64) {
                int src = csr_src[i];
                float lw = csr_lew[i];
#pragma unroll
                for (int h = 0; h < H; h++)
                    mx[h] = fmaxf(mx[h], leaky01(qa[(size_t)src * H + h] + qd[h] + lw));
            }
#pragma unroll
            for (int h = 0; h < H; h++) {
                for (int off = 32; off > 0; off >>= 1)
                    mx[h] = fmaxf(mx[h], __shfl_xor(mx[h], off, 64));
            }
            float sm[H];
#pragma unroll
            for (int h = 0; h < H; h++) sm[h] = 0.f;
            for (int i = beg + l; i < end; i += 64) {
                int src = csr_src[i];
                float lw = csr_lew[i];
#pragma unroll
                for (int h = 0; h < H; h++)
                    sm[h] += __expf(leaky01(qa[(size_t)src * H + h] + qd[h] + lw) - mx[h]);
            }
#pragma unroll
            for (int h = 0; h < H; h++) {
                for (int off = 32; off > 0; off >>= 1)
                    sm[h] += __shfl_xor(sm[h], off, 64);
            }
            float inv[H];
#pragma unroll
            for (int h = 0; h < H; h++) inv[h] = 1.f / fmaxf(sm[h], 1e-20f);

            for (int c0 = 0; c0 < deg; c0 += 64) {
                int cn = min(64, deg - c0);
                if (l < cn) {
                    int src = csr_src[beg + c0 + l];
                    float lw = csr_lew[beg + c0 + l];
                    sh_src[w][l] = src;
#pragma unroll
                    for (int h = 0; h < H; h++)
                        sh_sc[w][l * H + h] =
                            __expf(leaky01(qa[(size_t)src * H + h] + qd[h] + lw) - mx[h]) * inv[h];
                }
                for (int i = 0; i < cn; i++) {
                    int s0 = sh_src[w][i];
                    float a0 = sh_sc[w][i * H + hh];
                    if (VW == 4) {
                        float4 v0 = *(const float4*)&feat[(size_t)s0 * M + c];
                        acc0[0] += a0 * v0.x; acc0[1] += a0 * v0.y;
                        acc0[2] += a0 * v0.z; acc0[3] += a0 * v0.w;
                    } else {
                        float2 v0 = *(const float2*)&feat[(size_t)s0 * M + c];
                        acc0[0] += a0 * v0.x; acc0[1] += a0 * v0.y;
                    }
                }
            }
        }
    }

#pragma unroll
    for (int j = 0; j < VW; j++) {
        float r = acc0[j] + acc1[j] + bias[c + j];
        if (LOUT) r = leaky01(r);
        out[(size_t)n * M + c + j] = r;
    }
}

// ---------------- fused predictor v8 (R8-proven): 256 threads / 128 pairs ----------------
__global__ __launch_bounds__(256) void k_predf6(const float* __restrict__ h2,
                                                const int* __restrict__ ps, const int* __restrict__ pd,
                                                const int* __restrict__ ns, const int* __restrict__ nd,
                                                const float* __restrict__ W1, const float* __restrict__ b1,
                                                const float* __restrict__ W2, const float* __restrict__ b2,
                                                const float* __restrict__ W3, const float* __restrict__ b3,
                                                float* __restrict__ out, int npos, int ntot) {
    __shared__ float Zs[128 * 36];   // Z chunk [pair][36]; reused as T1-half [pair][32+pad]
    __shared__ float Wc[32 * 68];    // W1 chunk [k][out]
    __shared__ int sp[128], dp[128];

    int t = threadIdx.x;
    int p0 = blockIdx.x * 128;
    int ty2 = t >> 3;       // 0..31 pair groups: pairs ty2 + 32*i, i<4
    int tx2 = t & 7;        // 0..7 out groups: outs tx2*8..+7

    if (t < 128) {
        int pr = p0 + t;
        int s = 0, d = 0;
        if (pr < ntot) {
            if (pr < npos) { s = ps[pr]; d = pd[pr]; }
            else           { s = ns[pr - npos]; d = nd[pr - npos]; }
        }
        sp[t] = s; dp[t] = d;
    }
    __syncthreads();

    float acc[4][8];
#pragma unroll
    for (int i = 0; i < 4; i++)
#pragma unroll
        for (int j = 0; j < 8; j++) acc[i][j] = 0.f;

    int sr = t >> 3;        // staging row within sweep (0..31)
    int sq = t & 7;         // staging quad (0..7)

    for (int kc = 0; kc < 128; kc += 32) {
        // stage Z chunk: 4 sweeps x 32 rows, 8 threads/row (float4 each)
#pragma unroll
        for (int it = 0; it < 4; ++it) {
            int r = it * 32 + sr;
            int s = sp[r], d = dp[r];
            float4 a = *(const float4*)&h2[(size_t)s * 128 + kc + sq * 4];
            float4 b = *(const float4*)&h2[(size_t)d * 128 + kc + sq * 4];
            *(float4*)&Zs[r * 36 + sq * 4] =
                make_float4(a.x * b.x, a.y * b.y, a.z * b.z, a.w * b.w);
        }
        // stage W1 chunk [32 k][64 outs]
        {
            int out_ = t & 63;
            int kh = (t >> 6) * 8;
            const float* wr = W1 + (size_t)out_ * 128 + kc + kh;
#pragma unroll
            for (int c = 0; c < 2; c++) {
                float4 wv = *(const float4*)(wr + c * 4);
                Wc[(kh + c * 4 + 0) * 68 + out_] = wv.x;
                Wc[(kh + c * 4 + 1) * 68 + out_] = wv.y;
                Wc[(kh + c * 4 + 2) * 68 + out_] = wv.z;
                Wc[(kh + c * 4 + 3) * 68 + out_] = wv.w;
            }
        }
        __syncthreads();
#pragma unroll
        for (int k4 = 0; k4 < 8; ++k4) {
            float4 a4[4];
#pragma unroll
            for (int i = 0; i < 4; i++)
                a4[i] = *(const float4*)&Zs[(ty2 + 32 * i) * 36 + k4 * 4];
#pragma unroll
            for (int kk = 0; kk < 4; ++kk) {
                float4 bA = *(const float4*)&Wc[(k4 * 4 + kk) * 68 + tx2 * 8];
                float4 bB = *(const float4*)&Wc[(k4 * 4 + kk) * 68 + tx2 * 8 + 4];
                float bv[8] = {bA.x, bA.y, bA.z, bA.w, bB.x, bB.y, bB.z, bB.w};
#pragma unroll
                for (int i = 0; i < 4; i++) {
                    float a = (kk == 0) ? a4[i].x : (kk == 1) ? a4[i].y : (kk == 2) ? a4[i].z : a4[i].w;
#pragma unroll
                    for (int j = 0; j < 8; j++) acc[i][j] += a * bv[j];
                }
            }
        }
        __syncthreads();
    }

    // bias (pre-activation kept in acc)
    {
        float4 b1a = *(const float4*)&b1[tx2 * 8];
        float4 b1b = *(const float4*)&b1[tx2 * 8 + 4];
        float bb[8] = {b1a.x, b1a.y, b1a.z, b1a.w, b1b.x, b1b.y, b1b.z, b1b.w};
#pragma unroll
        for (int i = 0; i < 4; i++)
#pragma unroll
            for (int j = 0; j < 8; j++) acc[i][j] += bb[j];
    }

    float t2[32];
#pragma unroll
    for (int o = 0; o < 32; o++) t2[o] = b2[o];

    // ---- half A: outs 0..31 (written by tx2 0..3) ----
    if (tx2 < 4) {
#pragma unroll
        for (int i = 0; i < 4; i++) {
            int row = ty2 + 32 * i;
            *(float4*)&Zs[row * 36 + tx2 * 8] =
                make_float4(acc[i][0], acc[i][1], acc[i][2], acc[i][3]);
            *(float4*)&Zs[row * 36 + tx2 * 8 + 4] =
                make_float4(acc[i][4], acc[i][5], acc[i][6], acc[i][7]);
        }
    }
    __syncthreads();
    if (t < 128) {
        for (int j = 0; j < 32; j += 4) {
            float4 v4 = *(const float4*)&Zs[t * 36 + j];
            float v0 = leaky02(v4.x), v1 = leaky02(v4.y), v2 = leaky02(v4.z), v3 = leaky02(v4.w);
#pragma unroll
            for (int o = 0; o < 32; o++) {
                const float* w2 = W2 + (size_t)o * 64 + j;
                t2[o] += v0 * w2[0] + v1 * w2[1] + v2 * w2[2] + v3 * w2[3];
            }
        }
    }
    __syncthreads();
    // ---- half B: outs 32..63 (written by tx2 4..7) ----
    if (tx2 >= 4) {
#pragma unroll
        for (int i = 0; i < 4; i++) {
            int row = ty2 + 32 * i;
            *(float4*)&Zs[row * 36 + (tx2 - 4) * 8] =
                make_float4(acc[i][0], acc[i][1], acc[i][2], acc[i][3]);
            *(float4*)&Zs[row * 36 + (tx2 - 4) * 8 + 4] =
                make_float4(acc[i][4], acc[i][5], acc[i][6], acc[i][7]);
        }
    }
    __syncthreads();
    if (t < 128) {
        for (int j = 0; j < 32; j += 4) {
            float4 v4 = *(const float4*)&Zs[t * 36 + j];
            float v0 = leaky02(v4.x), v1 = leaky02(v4.y), v2 = leaky02(v4.z), v3 = leaky02(v4.w);
#pragma unroll
            for (int o = 0; o < 32; o++) {
                const float* w2 = W2 + (size_t)o * 64 + 32 + j;
                t2[o] += v0 * w2[0] + v1 * w2[1] + v2 * w2[2] + v3 * w2[3];
            }
        }
        float o3 = b3[0];
#pragma unroll
        for (int o = 0; o < 32; o++) o3 += leaky02(t2[o]) * W3[o];
        if (p0 + t < ntot) out[p0 + t] = o3;
    }
}

extern "C" void kernel_launch(void* const* d_in, const int* in_sizes, int n_in,
                              void* d_out, int out_size, void* d_ws, size_t ws_size,
                              hipStream_t stream) {
    const float* x    = (const float*)d_in[0];
    const float* ew   = (const float*)d_in[1];
    const int* esrc   = (const int*)d_in[2];
    const int* edst   = (const int*)d_in[3];
    const int* pos_s  = (const int*)d_in[4];
    const int* pos_d  = (const int*)d_in[5];
    const int* neg_s  = (const int*)d_in[6];
    const int* neg_d  = (const int*)d_in[7];
    const float* W0 = (const float*)d_in[8];
    const float* a0 = (const float*)d_in[9];
    const float* b0 = (const float*)d_in[10];
    const float* W1 = (const float*)d_in[11];
    const float* a1 = (const float*)d_in[12];
    const float* b1 = (const float*)d_in[13];
    const float* W2 = (const float*)d_in[14];
    const float* a2 = (const float*)d_in[15];
    const float* b2 = (const float*)d_in[16];
    const float* pW1 = (const float*)d_in[17];
    const float* pb1 = (const float*)d_in[18];
    const float* pW2 = (const float*)d_in[19];
    const float* pb2 = (const float*)d_in[20];
    const float* pW3 = (const float*)d_in[21];
    const float* pb3 = (const float*)d_in[22];

    const int N = in_sizes[0] / N_IN;   // 25000
    const int E = in_sizes[1];          // 400000
    const int NP = in_sizes[4];         // 100000

    size_t off = 0;
    auto alloc = [&](size_t bytes) {
        void* p = (char*)d_ws + off;
        off += (bytes + 255) & ~(size_t)255;
        return p;
    };
    int* deg      = (int*)alloc((size_t)N * 4);
    int* cursor   = (int*)alloc((size_t)N * 4);
    int* rowptr   = (int*)alloc((size_t)(N + 1) * 4);
    int* bsum     = (int*)alloc(512);
    int* boff     = (int*)alloc(512);
    int* csr_eid  = (int*)alloc((size_t)E * 4);
    int* csr_src  = (int*)alloc((size_t)E * 4);
    float* csr_lew = (float*)alloc((size_t)E * 4);
    float* qa     = (float*)alloc((size_t)N * 4 * 4);
    float* A      = (float*)alloc((size_t)N * 256 * 4);
    float* B      = (float*)alloc((size_t)N * 256 * 4);
    (void)ws_size; (void)n_in; (void)out_size;

    float* out_pred = (float*)d_out;              // [200000]
    float* emb      = (float*)d_out + 2 * NP;     // [25000 x 128]

    hipMemsetAsync(deg, 0, (size_t)N * 4, stream);
    hipMemsetAsync(cursor, 0, (size_t)N * 4, stream);

    int eb = (E + 255) / 256;
    int nb = (N + 255) / 256;   // 98
    k_count<<<eb, 256, 0, stream>>>(edst, deg, E);
    k_scan1<<<nb, 256, 0, stream>>>(deg, rowptr, bsum, N);
    k_scan2<<<1, 128, 0, stream>>>(bsum, boff, nb);
    k_scan3<<<nb, 256, 0, stream>>>(rowptr, boff, N);
    k_fill<<<eb, 256, 0, stream>>>(esrc, edst, ew, rowptr, cursor, csr_eid, csr_src, csr_lew, E);
    k_sortw<<<(N + 3) / 4, 256, 0, stream>>>(rowptr, csr_eid, csr_src, csr_lew, N);

    int rb = (N + 63) / 64;     // 391 row blocks
    int sb = (N + 3) / 4;       // wave-per-node blocks

    // layer 0: K=128, M=256
    k_gemm<<<dim3(2, rb), 256, 0, stream>>>(x, W0, A, N, 128, 256, a0, qa, 4, 64);
    k_fagg<4, 64, 4, true><<<sb, 256, 0, stream>>>(A, qa, b0, rowptr, csr_src, csr_lew, B, N);

    // layer 1: K=256, M=256
    k_gemm<<<dim3(2, rb), 256, 0, stream>>>(B, W1, A, N, 256, 256, a1, qa, 4, 64);
    k_fagg<4, 64, 4, true><<<sb, 256, 0, stream>>>(A, qa, b1, rowptr, csr_src, csr_lew, B, N);

    // layer 2: K=256, M=128
    k_gemm<<<dim3(1, rb), 256, 0, stream>>>(B, W2, A, N, 256, 128, a2, qa, 1, 128);
    k_fagg<1, 128, 2, false><<<sb, 256, 0, stream>>>(A, qa, b2, rowptr, csr_src, csr_lew, emb, N);

    // fused predictor on 2*NP pairs
    int ntot = 2 * NP;
    k_predf6<<<(ntot + 127) / 128, 256, 0, stream>>>(emb, pos_s, pos_d, neg_s, neg_d,
                                                     pW1, pb1, pW2, pb2, pW3, pb3,
                                                     out_pred, NP, ntot);
}

// Round 15
// 427.405 us; speedup vs baseline: 1.7882x; 1.0294x over previous
//
#include <hip/hip_runtime.h>
#include <math.h>
#include <limits.h>

#define N_IN 128

__device__ __forceinline__ float leaky01(float x) { return x >= 0.f ? x : 0.01f * x; }
__device__ __forceinline__ float leaky02(float x) { return x >= 0.f ? x : 0.2f * x; }

// ---------------- CSR build (packed int4: {eid, src, lew_bits, 0}) ----------------
__global__ void k_count(const int* __restrict__ edst, int* __restrict__ deg, int E) {
    int e = blockIdx.x * 256 + threadIdx.x;
    if (e < E) atomicAdd(&deg[edst[e]], 1);
}

__global__ void k_scan1(const int* __restrict__ deg, int* __restrict__ rowptr,
                        int* __restrict__ bsum, int n) {
    __shared__ int s[256];
    int b = blockIdx.x, t = threadIdx.x;
    int idx = b * 256 + t;
    int v = (idx < n) ? deg[idx] : 0;
    s[t] = v;
    __syncthreads();
    for (int off = 1; off < 256; off <<= 1) {
        int x = (t >= off) ? s[t - off] : 0;
        __syncthreads();
        s[t] += x;
        __syncthreads();
    }
    if (idx < n) rowptr[idx + 1] = s[t];
    if (t == 255) bsum[b] = s[255];
}

__global__ void k_scan2(const int* __restrict__ bsum, int* __restrict__ boff, int nb) {
    __shared__ int s[128];
    int t = threadIdx.x;
    int v = (t < nb) ? bsum[t] : 0;
    s[t] = v;
    __syncthreads();
    for (int off = 1; off < 128; off <<= 1) {
        int x = (t >= off) ? s[t - off] : 0;
        __syncthreads();
        s[t] += x;
        __syncthreads();
    }
    if (t < nb) boff[t] = s[t] - v;   // exclusive
}

__global__ void k_scan3(int* __restrict__ rowptr, const int* __restrict__ boff, int n) {
    int idx = blockIdx.x * 256 + threadIdx.x;
    if (idx < n) rowptr[idx + 1] += boff[idx >> 8];
    if (idx == 0) rowptr[0] = 0;
}

__global__ void k_fill(const int* __restrict__ esrc, const int* __restrict__ edst,
                       const float* __restrict__ ew, const int* __restrict__ rowptr,
                       int* __restrict__ cursor, int4* __restrict__ csr, int E) {
    int e = blockIdx.x * 256 + threadIdx.x;
    if (e >= E) return;
    int d = edst[e];
    int slot = rowptr[d] + atomicAdd(&cursor[d], 1);
    csr[slot] = make_int4(e, esrc[e], __float_as_int(log1pf(ew[e])), 0);
}

// wave-parallel deterministic segment sort on packed records
__global__ __launch_bounds__(256) void k_sortw(const int* __restrict__ rowptr,
                                               int4* __restrict__ csr, int n) {
    int w = threadIdx.x >> 6, l = threadIdx.x & 63;
    int v = blockIdx.x * 4 + w;
    if (v >= n) return;
    int b = rowptr[v], e = rowptr[v + 1];
    int deg = e - b;
    if (deg <= 1) return;
    if (deg <= 64) {
        int4 rec = make_int4(INT_MAX, 0, 0, 0);
        if (l < deg) rec = csr[b + l];
        int rank = 0;
        for (int j = 0; j < 64; j++) {
            int ej = __shfl(rec.x, j, 64);
            rank += (ej < rec.x) ? 1 : 0;
        }
        if (l < deg) csr[b + rank] = rec;
    } else if (l == 0) {
        for (int i = b + 1; i < e; i++) {
            int4 k = csr[i];
            int j = i - 1;
            while (j >= b && csr[j].x > k.x) {
                csr[j + 1] = csr[j];
                j--;
            }
            csr[j + 1] = k;
        }
    }
}

// ---------------- fp32 GEMM v2: tile 64x128, KT=16, fused qa ----------------
__global__ __launch_bounds__(256) void k_gemm(const float* __restrict__ X,
                                              const float* __restrict__ W,
                                              float* __restrict__ C,
                                              int N, int K, int M,
                                              const float* __restrict__ avec,
                                              float* __restrict__ qaOut,
                                              int H, int F) {
    __shared__ float Xs[16][68];
    __shared__ float Ws[16][132];
    __shared__ float qred[64][17];
    int r0 = blockIdx.y * 64;
    int c0 = blockIdx.x * 128;
    int t = threadIdx.x;
    int ty = t >> 4, tx = t & 15;

    float acc[4][8];
#pragma unroll
    for (int i = 0; i < 4; i++)
#pragma unroll
        for (int j = 0; j < 8; j++) acc[i][j] = 0.f;

    int lr = t >> 2;
    int lk = (t & 3) * 4;
    bool xok = (r0 + lr) < N;
    const float* Xp = X + (size_t)(r0 + lr) * K + lk;
    int wr = t >> 1;
    int wk = (t & 1) * 8;
    const float* Wp = W + (size_t)(c0 + wr) * K + wk;

    for (int k0 = 0; k0 < K; k0 += 16) {
        float4 xv = xok ? *(const float4*)(Xp + k0) : make_float4(0.f, 0.f, 0.f, 0.f);
        float4 wv0 = *(const float4*)(Wp + k0);
        float4 wv1 = *(const float4*)(Wp + k0 + 4);
        __syncthreads();
        Xs[lk + 0][lr] = xv.x; Xs[lk + 1][lr] = xv.y;
        Xs[lk + 2][lr] = xv.z; Xs[lk + 3][lr] = xv.w;
        Ws[wk + 0][wr] = wv0.x; Ws[wk + 1][wr] = wv0.y;
        Ws[wk + 2][wr] = wv0.z; Ws[wk + 3][wr] = wv0.w;
        Ws[wk + 4][wr] = wv1.x; Ws[wk + 5][wr] = wv1.y;
        Ws[wk + 6][wr] = wv1.z; Ws[wk + 7][wr] = wv1.w;
        __syncthreads();
#pragma unroll
        for (int k = 0; k < 16; k++) {
            float4 a = *(const float4*)&Xs[k][ty * 4];
            float4 b0 = *(const float4*)&Ws[k][tx * 8];
            float4 b1 = *(const float4*)&Ws[k][tx * 8 + 4];
            float av[4] = {a.x, a.y, a.z, a.w};
            float bv[8] = {b0.x, b0.y, b0.z, b0.w, b1.x, b1.y, b1.z, b1.w};
#pragma unroll
            for (int i = 0; i < 4; i++)
#pragma unroll
                for (int j = 0; j < 8; j++) acc[i][j] += av[i] * bv[j];
        }
    }

#pragma unroll
    for (int i = 0; i < 4; i++) {
        int row = r0 + ty * 4 + i;
        if (row < N) {
            float4 v0 = make_float4(acc[i][0], acc[i][1], acc[i][2], acc[i][3]);
            float4 v1 = make_float4(acc[i][4], acc[i][5], acc[i][6], acc[i][7]);
            *(float4*)&C[(size_t)row * M + c0 + tx * 8] = v0;
            *(float4*)&C[(size_t)row * M + c0 + tx * 8 + 4] = v1;
        }
    }

    if (qaOut) {
        int f0 = (c0 + tx * 8) & (F - 1);
        float4 a0 = *(const float4*)&avec[f0];
        float4 a1 = *(const float4*)&avec[f0 + 4];
#pragma unroll
        for (int i = 0; i < 4; i++) {
            float s = acc[i][0] * a0.x + acc[i][1] * a0.y + acc[i][2] * a0.z + acc[i][3] * a0.w
                    + acc[i][4] * a1.x + acc[i][5] * a1.y + acc[i][6] * a1.z + acc[i][7] * a1.w;
            qred[ty * 4 + i][tx] = s;
        }
        __syncthreads();
        if (t < 64) {
            int R = r0 + t;
            if (R < N) {
                float s0 = 0.f, s1 = 0.f;
#pragma unroll
                for (int x = 0; x < 8; x++) { s0 += qred[t][x]; s1 += qred[t][x + 8]; }
                if (F == 64) {
                    int hb = c0 >> 6;
                    qaOut[(size_t)R * H + hb] = s0;
                    qaOut[(size_t)R * H + hb + 1] = s1;
                } else {
                    qaOut[R] = s0 + s1;
                }
            }
        }
    }
}

// ---------------- fused softmax-stats + aggregation (packed CSR) ----------------
template <int H, int F, int VW, bool LOUT>
__global__ __launch_bounds__(256) void k_fagg(const float* __restrict__ feat,
                                              const float* __restrict__ qa,
                                              const float* __restrict__ bias,
                                              const int* __restrict__ rowptr,
                                              const int4* __restrict__ csr,
                                              float* __restrict__ out, int N) {
    constexpr int M = H * F;
    constexpr int CACHE = 128;
    constexpr int EPP = 64 / H;
    __shared__ int sh_src[4][CACHE];
    __shared__ float sh_sc[4][CACHE * H];
    int w = threadIdx.x >> 6, l = threadIdx.x & 63;
    int n = blockIdx.x * 4 + w;
    if (n >= N) return;
    int beg = rowptr[n];
    int deg = rowptr[n + 1] - beg;
    int c = l * VW;
    const int hh = c / F;

    float acc0[VW], acc1[VW];
#pragma unroll
    for (int j = 0; j < VW; j++) { acc0[j] = 0.f; acc1[j] = 0.f; }

    if (deg > 0) {
        if (deg <= CACHE) {
            const int e0 = l / H;
            const int h = l & (H - 1);
            float qd = qa[(size_t)n * H + h];
            float mx = -1e30f;
            for (int i0 = 0; i0 < deg; i0 += EPP) {
                int e = i0 + e0;
                if (e < deg) {
                    int4 q = csr[beg + e];
                    float lw = __int_as_float(q.z);
                    if (h == 0) sh_src[w][e] = q.y;
                    float sc = leaky01(qa[(size_t)q.y * H + h] + qd + lw);
                    sh_sc[w][e * H + h] = sc;
                    mx = fmaxf(mx, sc);
                }
            }
            for (int off = 32; off >= H; off >>= 1)
                mx = fmaxf(mx, __shfl_xor(mx, off, 64));
            float sm = 0.f;
            for (int i0 = 0; i0 < deg; i0 += EPP) {
                int e = i0 + e0;
                if (e < deg) sm += __expf(sh_sc[w][e * H + h] - mx);
            }
            for (int off = 32; off >= H; off >>= 1)
                sm += __shfl_xor(sm, off, 64);
            float inv = 1.f / fmaxf(sm, 1e-20f);
            for (int i0 = 0; i0 < deg; i0 += EPP) {
                int e = i0 + e0;
                if (e < deg)
                    sh_sc[w][e * H + h] = __expf(sh_sc[w][e * H + h] - mx) * inv;
            }
            int i = 0;
            for (; i + 4 <= deg; i += 4) {
                int s0 = sh_src[w][i], s1 = sh_src[w][i + 1];
                int s2 = sh_src[w][i + 2], s3 = sh_src[w][i + 3];
                float a0 = sh_sc[w][i * H + hh], a1 = sh_sc[w][(i + 1) * H + hh];
                float a2 = sh_sc[w][(i + 2) * H + hh], a3 = sh_sc[w][(i + 3) * H + hh];
                float f0[VW], f1[VW], f2[VW], f3[VW];
                if (VW == 4) {
                    float4 v0 = *(const float4*)&feat[(size_t)s0 * M + c];
                    float4 v1 = *(const float4*)&feat[(size_t)s1 * M + c];
                    float4 v2 = *(const float4*)&feat[(size_t)s2 * M + c];
                    float4 v3 = *(const float4*)&feat[(size_t)s3 * M + c];
                    f0[0] = v0.x; f0[1] = v0.y; f0[2] = v0.z; f0[3] = v0.w;
                    f1[0] = v1.x; f1[1] = v1.y; f1[2] = v1.z; f1[3] = v1.w;
                    f2[0] = v2.x; f2[1] = v2.y; f2[2] = v2.z; f2[3] = v2.w;
                    f3[0] = v3.x; f3[1] = v3.y; f3[2] = v3.z; f3[3] = v3.w;
                } else {
                    float2 v0 = *(const float2*)&feat[(size_t)s0 * M + c];
                    float2 v1 = *(const float2*)&feat[(size_t)s1 * M + c];
                    float2 v2 = *(const float2*)&feat[(size_t)s2 * M + c];
                    float2 v3 = *(const float2*)&feat[(size_t)s3 * M + c];
                    f0[0] = v0.x; f0[1] = v0.y;
                    f1[0] = v1.x; f1[1] = v1.y;
                    f2[0] = v2.x; f2[1] = v2.y;
                    f3[0] = v3.x; f3[1] = v3.y;
                }
#pragma unroll
                for (int j = 0; j < VW; j++) {
                    acc0[j] += a0 * f0[j] + a1 * f1[j];
                    acc1[j] += a2 * f2[j] + a3 * f3[j];
                }
            }
            for (; i < deg; ++i) {
                int s0 = sh_src[w][i];
                float a0 = sh_sc[w][i * H + hh];
                if (VW == 4) {
                    float4 v0 = *(const float4*)&feat[(size_t)s0 * M + c];
                    acc0[0] += a0 * v0.x; acc0[1] += a0 * v0.y;
                    acc0[2] += a0 * v0.z; acc0[3] += a0 * v0.w;
                } else {
                    float2 v0 = *(const float2*)&feat[(size_t)s0 * M + c];
                    acc0[0] += a0 * v0.x; acc0[1] += a0 * v0.y;
                }
            }
        } else {
            float qd[H];
#pragma unroll
            for (int h = 0; h < H; h++) qd[h] = qa[(size_t)n * H + h];
            int end = beg + deg;
            float mx[H];
#pragma unroll
            for (int h = 0; h < H; h++) mx[h] = -1e30f;
            for (int i = beg + l; i < end; i += 64) {
                int4 q = csr[i];
                float lw = __int_as_float(q.z);
#pragma unroll
                for (int h = 0; h < H; h++)
                    mx[h] = fmaxf(mx[h], leaky01(qa[(size_t)q.y * H + h] + qd[h] + lw));
            }
#pragma unroll
            for (int h = 0; h < H; h++) {
                for (int off = 32; off > 0; off >>= 1)
                    mx[h] = fmaxf(mx[h], __shfl_xor(mx[h], off, 64));
            }
            float sm[H];
#pragma unroll
            for (int h = 0; h < H; h++) sm[h] = 0.f;
            for (int i = beg + l; i < end; i += 64) {
                int4 q = csr[i];
                float lw = __int_as_float(q.z);
#pragma unroll
                for (int h = 0; h < H; h++)
                    sm[h] += __expf(leaky01(qa[(size_t)q.y * H + h] + qd[h] + lw) - mx[h]);
            }
#pragma unroll
            for (int h = 0; h < H; h++) {
                for (int off = 32; off > 0; off >>= 1)
                    sm[h] += __shfl_xor(sm[h], off, 64);
            }
            float inv[H];
#pragma unroll
            for (int h = 0; h < H; h++) inv[h] = 1.f / fmaxf(sm[h], 1e-20f);

            for (int c0 = 0; c0 < deg; c0 += 64) {
                int cn = min(64, deg - c0);
                if (l < cn) {
                    int4 q = csr[beg + c0 + l];
                    float lw = __int_as_float(q.z);
                    sh_src[w][l] = q.y;
#pragma unroll
                    for (int h = 0; h < H; h++)
                        sh_sc[w][l * H + h] =
                            __expf(leaky01(qa[(size_t)q.y * H + h] + qd[h] + lw) - mx[h]) * inv[h];
                }
                for (int i = 0; i < cn; i++) {
                    int s0 = sh_src[w][i];
                    float a0 = sh_sc[w][i * H + hh];
                    if (VW == 4) {
                        float4 v0 = *(const float4*)&feat[(size_t)s0 * M + c];
                        acc0[0] += a0 * v0.x; acc0[1] += a0 * v0.y;
                        acc0[2] += a0 * v0.z; acc0[3] += a0 * v0.w;
                    } else {
                        float2 v0 = *(const float2*)&feat[(size_t)s0 * M + c];
                        acc0[0] += a0 * v0.x; acc0[1] += a0 * v0.y;
                    }
                }
            }
        }
    }

#pragma unroll
    for (int j = 0; j < VW; j++) {
        float r = acc0[j] + acc1[j] + bias[c + j];
        if (LOUT) r = leaky01(r);
        out[(size_t)n * M + c + j] = r;
    }
}

// ---------------- fused predictor v9: 256 threads / 64 pairs ----------------
// Same chunked structure as predf6 at quarter tile: LDS 18.7KB -> 8 blocks/CU,
// grid 3125 -> doubled resident waves for the latency-bound gather phase.
__global__ __launch_bounds__(256) void k_predf7(const float* __restrict__ h2,
                                                const int* __restrict__ ps, const int* __restrict__ pd,
                                                const int* __restrict__ ns, const int* __restrict__ nd,
                                                const float* __restrict__ W1, const float* __restrict__ b1,
                                                const float* __restrict__ W2, const float* __restrict__ b2,
                                                const float* __restrict__ W3, const float* __restrict__ b3,
                                                float* __restrict__ out, int npos, int ntot) {
    __shared__ float Zs[64 * 36];    // Z chunk [pair][36]; reused as T1-half [pair][32+pad]
    __shared__ float Wc[32 * 68];    // W1 chunk [k][out]
    __shared__ int sp[64], dp[64];

    int t = threadIdx.x;
    int p0 = blockIdx.x * 64;
    int ty2 = t >> 3;       // 0..31 pair groups: pairs ty2 + 32*i, i<2
    int tx2 = t & 7;        // 0..7 out groups: outs tx2*8..+7

    if (t < 64) {
        int pr = p0 + t;
        int s = 0, d = 0;
        if (pr < ntot) {
            if (pr < npos) { s = ps[pr]; d = pd[pr]; }
            else           { s = ns[pr - npos]; d = nd[pr - npos]; }
        }
        sp[t] = s; dp[t] = d;
    }
    __syncthreads();

    float acc[2][8];
#pragma unroll
    for (int i = 0; i < 2; i++)
#pragma unroll
        for (int j = 0; j < 8; j++) acc[i][j] = 0.f;

    int sr = t >> 3;        // staging row within sweep (0..31)
    int sq = t & 7;         // staging quad (0..7)

    for (int kc = 0; kc < 128; kc += 32) {
        // stage Z chunk: 2 sweeps x 32 rows, 8 threads/row (float4 each)
#pragma unroll
        for (int it = 0; it < 2; ++it) {
            int r = it * 32 + sr;
            int s = sp[r], d = dp[r];
            float4 a = *(const float4*)&h2[(size_t)s * 128 + kc + sq * 4];
            float4 b = *(const float4*)&h2[(size_t)d * 128 + kc + sq * 4];
            *(float4*)&Zs[r * 36 + sq * 4] =
                make_float4(a.x * b.x, a.y * b.y, a.z * b.z, a.w * b.w);
        }
        // stage W1 chunk [32 k][64 outs]
        {
            int out_ = t & 63;
            int kh = (t >> 6) * 8;
            const float* wr = W1 + (size_t)out_ * 128 + kc + kh;
#pragma unroll
            for (int c = 0; c < 2; c++) {
                float4 wv = *(const float4*)(wr + c * 4);
                Wc[(kh + c * 4 + 0) * 68 + out_] = wv.x;
                Wc[(kh + c * 4 + 1) * 68 + out_] = wv.y;
                Wc[(kh + c * 4 + 2) * 68 + out_] = wv.z;
                Wc[(kh + c * 4 + 3) * 68 + out_] = wv.w;
            }
        }
        __syncthreads();
#pragma unroll
        for (int k4 = 0; k4 < 8; ++k4) {
            float4 a4[2];
#pragma unroll
            for (int i = 0; i < 2; i++)
                a4[i] = *(const float4*)&Zs[(ty2 + 32 * i) * 36 + k4 * 4];
#pragma unroll
            for (int kk = 0; kk < 4; ++kk) {
                float4 bA = *(const float4*)&Wc[(k4 * 4 + kk) * 68 + tx2 * 8];
                float4 bB = *(const float4*)&Wc[(k4 * 4 + kk) * 68 + tx2 * 8 + 4];
                float bv[8] = {bA.x, bA.y, bA.z, bA.w, bB.x, bB.y, bB.z, bB.w};
#pragma unroll
                for (int i = 0; i < 2; i++) {
                    float a = (kk == 0) ? a4[i].x : (kk == 1) ? a4[i].y : (kk == 2) ? a4[i].z : a4[i].w;
#pragma unroll
                    for (int j = 0; j < 8; j++) acc[i][j] += a * bv[j];
                }
            }
        }
        __syncthreads();
    }

    // bias (pre-activation kept in acc)
    {
        float4 b1a = *(const float4*)&b1[tx2 * 8];
        float4 b1b = *(const float4*)&b1[tx2 * 8 + 4];
        float bb[8] = {b1a.x, b1a.y, b1a.z, b1a.w, b1b.x, b1b.y, b1b.z, b1b.w};
#pragma unroll
        for (int i = 0; i < 2; i++)
#pragma unroll
            for (int j = 0; j < 8; j++) acc[i][j] += bb[j];
    }

    float t2[32];
#pragma unroll
    for (int o = 0; o < 32; o++) t2[o] = b2[o];

    // ---- half A: outs 0..31 (written by tx2 0..3) ----
    if (tx2 < 4) {
#pragma unroll
        for (int i = 0; i < 2; i++) {
            int row = ty2 + 32 * i;
            *(float4*)&Zs[row * 36 + tx2 * 8] =
                make_float4(acc[i][0], acc[i][1], acc[i][2], acc[i][3]);
            *(float4*)&Zs[row * 36 + tx2 * 8 + 4] =
                make_float4(acc[i][4], acc[i][5], acc[i][6], acc[i][7]);
        }
    }
    __syncthreads();
    if (t < 64) {
        for (int j = 0; j < 32; j += 4) {
            float4 v4 = *(const float4*)&Zs[t * 36 + j];
            float v0 = leaky02(v4.x), v1 = leaky02(v4.y), v2 = leaky02(v4.z), v3 = leaky02(v4.w);
#pragma unroll
            for (int o = 0; o < 32; o++) {
                const float* w2 = W2 + (size_t)o * 64 + j;
                t2[o] += v0 * w2[0] + v1 * w2[1] + v2 * w2[2] + v3 * w2[3];
            }
        }
    }
    __syncthreads();
    // ---- half B: outs 32..63 (written by tx2 4..7) ----
    if (tx2 >= 4) {
#pragma unroll
        for (int i = 0; i < 2; i++) {
            int row = ty2 + 32 * i;
            *(float4*)&Zs[row * 36 + (tx2 - 4) * 8] =
                make_float4(acc[i][0], acc[i][1], acc[i][2], acc[i][3]);
            *(float4*)&Zs[row * 36 + (tx2 - 4) * 8 + 4] =
                make_float4(acc[i][4], acc[i][5], acc[i][6], acc[i][7]);
        }
    }
    __syncthreads();
    if (t < 64) {
        for (int j = 0; j < 32; j += 4) {
            float4 v4 = *(const float4*)&Zs[t * 36 + j];
            float v0 = leaky02(v4.x), v1 = leaky02(v4.y), v2 = leaky02(v4.z), v3 = leaky02(v4.w);
#pragma unroll
            for (int o = 0; o < 32; o++) {
                const float* w2 = W2 + (size_t)o * 64 + 32 + j;
                t2[o] += v0 * w2[0] + v1 * w2[1] + v2 * w2[2] + v3 * w2[3];
            }
        }
        float o3 = b3[0];
#pragma unroll
        for (int o = 0; o < 32; o++) o3 += leaky02(t2[o]) * W3[o];
        if (p0 + t < ntot) out[p0 + t] = o3;
    }
}

extern "C" void kernel_launch(void* const* d_in, const int* in_sizes, int n_in,
                              void* d_out, int out_size, void* d_ws, size_t ws_size,
                              hipStream_t stream) {
    const float* x    = (const float*)d_in[0];
    const float* ew   = (const float*)d_in[1];
    const int* esrc   = (const int*)d_in[2];
    const int* edst   = (const int*)d_in[3];
    const int* pos_s  = (const int*)d_in[4];
    const int* pos_d  = (const int*)d_in[5];
    const int* neg_s  = (const int*)d_in[6];
    const int* neg_d  = (const int*)d_in[7];
    const float* W0 = (const float*)d_in[8];
    const float* a0 = (const float*)d_in[9];
    const float* b0 = (const float*)d_in[10];
    const float* W1 = (const float*)d_in[11];
    const float* a1 = (const float*)d_in[12];
    const float* b1 = (const float*)d_in[13];
    const float* W2 = (const float*)d_in[14];
    const float* a2 = (const float*)d_in[15];
    const float* b2 = (const float*)d_in[16];
    const float* pW1 = (const float*)d_in[17];
    const float* pb1 = (const float*)d_in[18];
    const float* pW2 = (const float*)d_in[19];
    const float* pb2 = (const float*)d_in[20];
    const float* pW3 = (const float*)d_in[21];
    const float* pb3 = (const float*)d_in[22];

    const int N = in_sizes[0] / N_IN;   // 25000
    const int E = in_sizes[1];          // 400000
    const int NP = in_sizes[4];         // 100000

    size_t off = 0;
    auto alloc = [&](size_t bytes) {
        void* p = (char*)d_ws + off;
        off += (bytes + 255) & ~(size_t)255;
        return p;
    };
    int* deg      = (int*)alloc((size_t)N * 4);
    int* cursor   = (int*)alloc((size_t)N * 4);
    int* rowptr   = (int*)alloc((size_t)(N + 1) * 4);
    int* bsum     = (int*)alloc(512);
    int* boff     = (int*)alloc(512);
    int4* csr     = (int4*)alloc((size_t)E * 16);
    float* qa     = (float*)alloc((size_t)N * 4 * 4);
    float* A      = (float*)alloc((size_t)N * 256 * 4);
    float* B      = (float*)alloc((size_t)N * 256 * 4);
    (void)ws_size; (void)n_in; (void)out_size;

    float* out_pred = (float*)d_out;              // [200000]
    float* emb      = (float*)d_out + 2 * NP;     // [25000 x 128]

    hipMemsetAsync(deg, 0, (size_t)N * 4, stream);
    hipMemsetAsync(cursor, 0, (size_t)N * 4, stream);

    int eb = (E + 255) / 256;
    int nb = (N + 255) / 256;   // 98
    k_count<<<eb, 256, 0, stream>>>(edst, deg, E);
    k_scan1<<<nb, 256, 0, stream>>>(deg, rowptr, bsum, N);
    k_scan2<<<1, 128, 0, stream>>>(bsum, boff, nb);
    k_scan3<<<nb, 256, 0, stream>>>(rowptr, boff, N);
    k_fill<<<eb, 256, 0, stream>>>(esrc, edst, ew, rowptr, cursor, csr, E);
    k_sortw<<<(N + 3) / 4, 256, 0, stream>>>(rowptr, csr, N);

    int rb = (N + 63) / 64;     // 391 row blocks
    int sb = (N + 3) / 4;       // wave-per-node blocks

    // layer 0: K=128, M=256
    k_gemm<<<dim3(2, rb), 256, 0, stream>>>(x, W0, A, N, 128, 256, a0, qa, 4, 64);
    k_fagg<4, 64, 4, true><<<sb, 256, 0, stream>>>(A, qa, b0, rowptr, csr, B, N);

    // layer 1: K=256, M=256
    k_gemm<<<dim3(2, rb), 256, 0, stream>>>(B, W1, A, N, 256, 256, a1, qa, 4, 64);
    k_fagg<4, 64, 4, true><<<sb, 256, 0, stream>>>(A, qa, b1, rowptr, csr, B, N);

    // layer 2: K=256, M=128
    k_gemm<<<dim3(1, rb), 256, 0, stream>>>(B, W2, A, N, 256, 128, a2, qa, 1, 128);
    k_fagg<1, 128, 2, false><<<sb, 256, 0, stream>>>(A, qa, b2, rowptr, csr, emb, N);

    // fused predictor on 2*NP pairs
    int ntot = 2 * NP;
    k_predf7<<<(ntot + 63) / 64, 256, 0, stream>>>(emb, pos_s, pos_d, neg_s, neg_d,
                                                   pW1, pb1, pW2, pb2, pW3, pb3,
                                                   out_pred, NP, ntot);
}